// Round 14
// baseline (263.961 us; speedup 1.0000x reference)
//
#include <hip/hip_runtime.h>
#include <math.h>

#define NEG_SLOPE 0.2f
__device__ __forceinline__ float lrelu(float x){ return x >= 0.f ? x : NEG_SLOPE * x; }

typedef __attribute__((ext_vector_type(8))) short bf16x8;
typedef __attribute__((ext_vector_type(4))) float f32x4;

__device__ __forceinline__ float wred_sum(float v){
  #pragma unroll
  for (int o = 32; o; o >>= 1) v += __shfl_xor(v, o, 64);
  return v;
}

__device__ __forceinline__ float bfhi_f(float f){
  return __uint_as_float(__float_as_uint(f) & 0xFFFF0000u);
}
// fp32 -> bf16 RTNE
__device__ __forceinline__ unsigned short f2bf(float f){
  unsigned u = __float_as_uint(f);
  unsigned r = u + 0x7FFFu + ((u >> 16) & 1u);
  return (unsigned short)(r >> 16);
}

// ================= bucketed CSR build =================
__global__ __launch_bounds__(256) void k_bincnt(const int* __restrict__ ei, int E, int N, int nb,
                                                unsigned* __restrict__ bcnt){
  __shared__ unsigned h[512];
  const int tot = E + N;
  for (int i = threadIdx.x; i < nb; i += 256) h[i] = 0;
  __syncthreads();
  int base = blockIdx.x * 8192;
  #pragma unroll 4
  for (int j = 0; j < 32; j++){
    int e = base + threadIdx.x + j * 256;
    if (e < tot){
      unsigned d = (e < E) ? (unsigned)ei[E + e] : (unsigned)(e - E);
      atomicAdd(&h[d >> 8], 1u);
    }
  }
  __syncthreads();
  for (int i = threadIdx.x; i < nb; i += 256)
    if (h[i]) atomicAdd(&bcnt[i], h[i]);
}

__global__ void k_bscan(const unsigned* __restrict__ bcnt, unsigned* __restrict__ bbase,
                        unsigned* __restrict__ bcur, int nb, int tot){
  __shared__ unsigned s[512];
  int t = threadIdx.x;
  unsigned v = (t < nb) ? bcnt[t] : 0u;
  s[t] = v; __syncthreads();
  for (int off = 1; off < 512; off <<= 1){
    unsigned x = (t >= off) ? s[t - off] : 0u; __syncthreads();
    s[t] += x; __syncthreads();
  }
  if (t < nb){ unsigned b = s[t] - v; bbase[t] = b; bcur[t] = b; }
  if (t == 0) bbase[nb] = (unsigned)tot;
}

__global__ __launch_bounds__(256) void k_binscat(const int* __restrict__ ei, int E, int N, int nb,
    unsigned* __restrict__ bcur, unsigned* __restrict__ staged){
  __shared__ unsigned sd[8192];
  __shared__ unsigned hist[512];
  __shared__ unsigned runb[512];
  const int tot = E + N;
  for (int i = threadIdx.x; i < nb; i += 256) hist[i] = 0;
  __syncthreads();
  int base = blockIdx.x * 8192;
  #pragma unroll 4
  for (int j = 0; j < 32; j++){
    int idx = threadIdx.x + j * 256;
    int e = base + idx;
    unsigned d = 0xFFFFFFFFu;
    if (e < tot) d = (e < E) ? (unsigned)ei[E + e] : (unsigned)(e - E);
    sd[idx] = d;
    if (d != 0xFFFFFFFFu) atomicAdd(&hist[d >> 8], 1u);
  }
  __syncthreads();
  for (int i = threadIdx.x; i < nb; i += 256){
    unsigned c = hist[i];
    runb[i] = c ? atomicAdd(&bcur[i], c) : 0u;
    hist[i] = 0;
  }
  __syncthreads();
  #pragma unroll 4
  for (int j = 0; j < 32; j++){
    int idx = threadIdx.x + j * 256;
    unsigned d = sd[idx];
    if (d == 0xFFFFFFFFu) continue;
    int e = base + idx;
    unsigned s = (e < E) ? (unsigned)ei[e] : d;
    unsigned b = d >> 8;
    unsigned pos = runb[b] + atomicAdd(&hist[b], 1u);
    staged[pos] = s | ((d & 255u) << 20);
  }
}

__global__ __launch_bounds__(256) void k_csr(const unsigned* __restrict__ bbase,
    const unsigned* __restrict__ staged, int N,
    unsigned* __restrict__ off_, unsigned* __restrict__ cur, int* __restrict__ srcids){
  __shared__ unsigned cnt[256], scn[256], cnt2[256];
  int b = blockIdx.x, t = threadIdx.x;
  unsigned beg = bbase[b], end = bbase[b + 1];
  cnt[t] = 0; cnt2[t] = 0;
  __syncthreads();
  for (unsigned i = beg + t; i < end; i += 256)
    atomicAdd(&cnt[staged[i] >> 20], 1u);
  __syncthreads();
  unsigned v = cnt[t];
  scn[t] = v; __syncthreads();
  for (int off = 1; off < 256; off <<= 1){
    unsigned x = (t >= off) ? scn[t - off] : 0u; __syncthreads();
    scn[t] += x; __syncthreads();
  }
  unsigned ex = scn[t] - v;
  int d = b * 256 + t;
  if (d < N){ off_[d] = beg + ex; cur[d] = beg + ex + v; }
  cnt[t] = ex;
  __syncthreads();
  for (unsigned i = beg + t; i < end; i += 256){
    unsigned u = staged[i];
    unsigned dl = u >> 20;
    unsigned pos = beg + cnt[dl] + atomicAdd(&cnt2[dl], 1u);
    srcids[pos] = (int)(u & 0xFFFFFu);
  }
}

// ============ W1 prep: Wt_hi/Wt_lo[64][256] bf16 ============
__global__ void k_wprep(const float* __restrict__ W, short* __restrict__ wt_hi,
                        short* __restrict__ wt_lo){
  int i = blockIdx.x * 256 + threadIdx.x;    // 16384
  int k = i >> 6, c = i & 63;
  float v = W[i];
  unsigned u = __float_as_uint(v);
  wt_hi[c * 256 + k] = (short)(u >> 16);
  float lo = v - bfhi_f(v);
  wt_lo[c * 256 + k] = (short)(__float_as_uint(lo) >> 16);
}

// ============ W2 prep: [48][64] bf16 hi/lo (cols 40-47 zero) ============
__global__ void k_w2prep(const float* __restrict__ W2, short* __restrict__ hi,
                         short* __restrict__ lo){
  int i = blockIdx.x * 256 + threadIdx.x;    // 3072
  if (i >= 48 * 64) return;
  int c = i >> 6, k = i & 63;
  float v = (c < 40) ? W2[k * 40 + c] : 0.f;
  unsigned u = __float_as_uint(v);
  hi[c * 64 + k] = (short)(u >> 16);
  float l = v - bfhi_f(v);
  lo[c * 64 + k] = (short)(__float_as_uint(l) >> 16);
}

// ============ GEMM1 via MFMA: contiguous-row global_load_lds staging ============
// Each of the wave's 16 gload_lds instructions covers ONE full 1KB row (64 lanes
// x 16B consecutive) -> 8 consecutive cache lines, uniform L2-channel spread.
// Previous variants gathered 16 lines at 1KB stride per instruction (channel
// camping -> 600 GB/s wall). gload_lds has no VGPR dest, so loads cannot be
// re-sunk by the register allocator (R9/R11/R12 failure). Rows padded +32B in
// LDS (each row is its own instruction base) -> ~conflict-free ds_read_b128.
__global__ __launch_bounds__(256) void k_gemm1_mfma(const float* __restrict__ x,
    const short* __restrict__ wt_hi, const short* __restrict__ wt_lo,
    const float* __restrict__ a1s, const float* __restrict__ a1d,
    unsigned short* __restrict__ h1b, float* __restrict__ as_, float* __restrict__ ad_, int N){
  __shared__ float lds[4][16 * 264];         // per-wave: 16 rows x (256+8) floats
  int lane = threadIdx.x & 63;
  int wv   = threadIdx.x >> 6;
  int r0   = blockIdx.x * 64 + wv * 16;
  if (r0 >= N) return;
  int col16 = lane & 15;
  int kg    = lane >> 4;
  float* ldsw = lds[wv];

  // stage the 16-row tile: one contiguous 1KB row per instruction
  #pragma unroll
  for (int rr = 0; rr < 16; rr++){
    const float* gsrc = x + (size_t)min(r0 + rr, N - 1) * 256 + lane * 4;
    __builtin_amdgcn_global_load_lds((const __attribute__((address_space(1))) void*)(const void*)gsrc,
                                     (__attribute__((address_space(3))) void*)(void*)(ldsw + rr * 264),
                                     16, 0, 0);
  }
  __builtin_amdgcn_sched_barrier(0);
  asm volatile("s_waitcnt vmcnt(0)" ::: "memory");
  __builtin_amdgcn_sched_barrier(0);

  f32x4 acc[4];
  #pragma unroll
  for (int ct = 0; ct < 4; ct++) acc[ct] = (f32x4){0.f, 0.f, 0.f, 0.f};

  const float* rp = ldsw + col16 * 264 + kg * 8;
  #pragma unroll 2
  for (int kt = 0; kt < 8; kt++){
    float4 v0 = *(const float4*)(rp + kt * 32);
    float4 v1 = *(const float4*)(rp + kt * 32 + 4);
    unsigned u[8] = {__float_as_uint(v0.x), __float_as_uint(v0.y), __float_as_uint(v0.z), __float_as_uint(v0.w),
                     __float_as_uint(v1.x), __float_as_uint(v1.y), __float_as_uint(v1.z), __float_as_uint(v1.w)};
    union { bf16x8 v; unsigned u[4]; } ahi, alo;
    #pragma unroll
    for (int j = 0; j < 4; j++)
      ahi.u[j] = __builtin_amdgcn_perm(u[2*j+1], u[2*j], 0x07060302);
    float lo[8];
    lo[0] = v0.x - bfhi_f(v0.x); lo[1] = v0.y - bfhi_f(v0.y);
    lo[2] = v0.z - bfhi_f(v0.z); lo[3] = v0.w - bfhi_f(v0.w);
    lo[4] = v1.x - bfhi_f(v1.x); lo[5] = v1.y - bfhi_f(v1.y);
    lo[6] = v1.z - bfhi_f(v1.z); lo[7] = v1.w - bfhi_f(v1.w);
    #pragma unroll
    for (int j = 0; j < 4; j++)
      alo.u[j] = __builtin_amdgcn_perm(__float_as_uint(lo[2*j+1]), __float_as_uint(lo[2*j]), 0x07060302);

    #pragma unroll
    for (int ct = 0; ct < 4; ct++){
      int wcol = ct * 16 + col16;
      const bf16x8 bhi = *(const bf16x8*)(wt_hi + wcol * 256 + kt * 32 + kg * 8);
      const bf16x8 blo = *(const bf16x8*)(wt_lo + wcol * 256 + kt * 32 + kg * 8);
      acc[ct] = __builtin_amdgcn_mfma_f32_16x16x32_bf16(ahi.v, bhi, acc[ct], 0, 0, 0);
      acc[ct] = __builtin_amdgcn_mfma_f32_16x16x32_bf16(ahi.v, blo, acc[ct], 0, 0, 0);
      acc[ct] = __builtin_amdgcn_mfma_f32_16x16x32_bf16(alo.v, bhi, acc[ct], 0, 0, 0);
    }
  }

  float cs[4], cd[4];
  #pragma unroll
  for (int ct = 0; ct < 4; ct++){ cs[ct] = a1s[ct * 16 + col16]; cd[ct] = a1d[ct * 16 + col16]; }
  #pragma unroll
  for (int r = 0; r < 4; r++){
    int rr = r0 + kg * 4 + r;
    bool ok = rr < N;
    #pragma unroll
    for (int ct = 0; ct < 4; ct++){
      float v = acc[ct][r];
      if (ok) h1b[(size_t)rr * 64 + ct * 16 + col16] = f2bf(v);
      float s = v * cs[ct];
      float t = v * cd[ct];
      s += __shfl_xor(s, 1, 64); s += __shfl_xor(s, 2, 64); s += __shfl_xor(s, 4, 64);
      t += __shfl_xor(t, 1, 64); t += __shfl_xor(t, 2, 64); t += __shfl_xor(t, 4, 64);
      if (ok && (col16 & 7) == 0){
        int head = ct * 2 + (col16 >> 3);
        as_[(size_t)rr * 8 + head] = s;
        ad_[(size_t)rr * 8 + head] = t;
      }
    }
  }
}

// ============ layer-1 per-dst gather: staged srcids, MLP-4 channel phase ============
__global__ __launch_bounds__(256) void k_gat1(const unsigned* __restrict__ off_, const unsigned* __restrict__ cur,
    const int* __restrict__ srcids, const float* __restrict__ as_, const float* __restrict__ ad_,
    const unsigned short* __restrict__ h1b, const float* __restrict__ b1,
    unsigned short* __restrict__ out1b, int N){
  int lane = threadIdx.x & 63;
  int wv   = threadIdx.x >> 6;
  int d    = blockIdx.x * 4 + wv;
  if (d >= N) return;
  __shared__ float lds_p[4][64 * 8];
  __shared__ int   lds_s[4][64];
  float* lp = lds_p[wv];
  int*   ls = lds_s[wv];
  unsigned beg = off_[d], fin = cur[d];

  int e8 = lane >> 3, h = lane & 7;                  // exp-phase layout
  int c0 = lane & 31, pe = lane >> 5, hh = c0 >> 2;  // channel-phase layout
  float adh = ad_[(size_t)d * 8 + h];
  float psacc = 0.f, accx = 0.f, accy = 0.f;

  for (unsigned base = beg; base < fin; base += 64){
    int nthis = (int)min(64u, fin - base);
    unsigned i = base + lane;
    ls[lane] = (i < fin) ? srcids[i] : 0;            // one coalesced stage
    asm volatile("s_waitcnt lgkmcnt(0)" ::: "memory");
    __builtin_amdgcn_sched_barrier(0);
    for (int j = 0; j < nthis; j += 8){
      int eloc = j + e8;
      int s = ls[eloc];
      float p = 0.f;
      if (eloc < nthis) p = __expf(lrelu(as_[(size_t)s * 8 + h] + adh));
      lp[eloc * 8 + h] = p;
      psacc += p;
    }
    asm volatile("s_waitcnt lgkmcnt(0)" ::: "memory");
    __builtin_amdgcn_sched_barrier(0);
    for (int e = 0; e < nthis; e += 8){
      int e0 = e + pe, e1 = e + 2 + pe, e2 = e + 4 + pe, e3 = e + 6 + pe;
      float p0 = lp[e0 * 8 + hh], p1 = lp[e1 * 8 + hh];
      float p2 = lp[e2 * 8 + hh], p3 = lp[e3 * 8 + hh];
      int s0 = ls[e0], s1 = ls[e1], s2 = ls[e2], s3 = ls[e3];
      unsigned u0 = *(const unsigned*)(h1b + (size_t)s0 * 64 + c0 * 2);
      unsigned u1 = *(const unsigned*)(h1b + (size_t)s1 * 64 + c0 * 2);
      unsigned u2 = *(const unsigned*)(h1b + (size_t)s2 * 64 + c0 * 2);
      unsigned u3 = *(const unsigned*)(h1b + (size_t)s3 * 64 + c0 * 2);
      accx = fmaf(p0, __uint_as_float(u0 << 16), accx);
      accy = fmaf(p0, __uint_as_float(u0 & 0xFFFF0000u), accy);
      accx = fmaf(p1, __uint_as_float(u1 << 16), accx);
      accy = fmaf(p1, __uint_as_float(u1 & 0xFFFF0000u), accy);
      accx = fmaf(p2, __uint_as_float(u2 << 16), accx);
      accy = fmaf(p2, __uint_as_float(u2 & 0xFFFF0000u), accy);
      accx = fmaf(p3, __uint_as_float(u3 << 16), accx);
      accy = fmaf(p3, __uint_as_float(u3 & 0xFFFF0000u), accy);
    }
    asm volatile("" ::: "memory");
  }
  float den = psacc;
  den += __shfl_xor(den, 8, 64);
  den += __shfl_xor(den, 16, 64);
  den += __shfl_xor(den, 32, 64);
  float mydenv = __shfl(den, hh, 64);
  accx += __shfl_xor(accx, 32, 64);
  accy += __shfl_xor(accy, 32, 64);
  if (lane < 32){
    int ch = lane * 2;
    float v0 = accx / mydenv + b1[ch];
    float v1 = accy / mydenv + b1[ch + 1];
    ushort2 o;
    o.x = f2bf(v0 > 0.f ? v0 : 0.f);
    o.y = f2bf(v1 > 0.f ? v1 : 0.f);
    *(ushort2*)(out1b + (size_t)d * 64 + ch) = o;
  }
}

// ============ GEMM2 via MFMA (bf16 A, hi/lo B) + fused alpha2 ============
__global__ __launch_bounds__(256) void k_gemm2m(const unsigned short* __restrict__ out1b,
    const short* __restrict__ wt2_hi, const short* __restrict__ wt2_lo,
    const float* __restrict__ a2s, const float* __restrict__ a2d,
    unsigned short* __restrict__ h2b, float* __restrict__ as_, float* __restrict__ ad_, int N){
  int lane = threadIdx.x & 63;
  int wv   = threadIdx.x >> 6;
  int r0   = blockIdx.x * 64 + wv * 16;
  if (r0 >= N) return;
  int col16 = lane & 15;
  int kg    = lane >> 4;
  const unsigned short* ar = out1b + (size_t)min(r0 + col16, N - 1) * 64 + kg * 8;

  f32x4 acc[3];
  #pragma unroll
  for (int ct = 0; ct < 3; ct++) acc[ct] = (f32x4){0.f, 0.f, 0.f, 0.f};

  #pragma unroll
  for (int kt = 0; kt < 2; kt++){
    const bf16x8 a = *(const bf16x8*)(ar + kt * 32);
    #pragma unroll
    for (int ct = 0; ct < 3; ct++){
      int wcol = ct * 16 + col16;
      const bf16x8 bhi = *(const bf16x8*)(wt2_hi + wcol * 64 + kt * 32 + kg * 8);
      const bf16x8 blo = *(const bf16x8*)(wt2_lo + wcol * 64 + kt * 32 + kg * 8);
      acc[ct] = __builtin_amdgcn_mfma_f32_16x16x32_bf16(a, bhi, acc[ct], 0, 0, 0);
      acc[ct] = __builtin_amdgcn_mfma_f32_16x16x32_bf16(a, blo, acc[ct], 0, 0, 0);
    }
  }

  float cs[3], cd[3];
  #pragma unroll
  for (int ct = 0; ct < 3; ct++){
    int col = ct * 16 + col16;
    bool okc = col < 40;
    cs[ct] = okc ? a2s[col] : 0.f;
    cd[ct] = okc ? a2d[col] : 0.f;
  }
  #pragma unroll
  for (int r = 0; r < 4; r++){
    int rr = r0 + kg * 4 + r;
    bool ok = rr < N;
    float s = 0.f, t = 0.f;
    #pragma unroll
    for (int ct = 0; ct < 3; ct++){
      s = fmaf(acc[ct][r], cs[ct], s);
      t = fmaf(acc[ct][r], cd[ct], t);
      int col = ct * 16 + col16;
      if (ok && col < 40) h2b[(size_t)rr * 40 + col] = f2bf(acc[ct][r]);
    }
    s += __shfl_xor(s, 1, 64); s += __shfl_xor(s, 2, 64);
    s += __shfl_xor(s, 4, 64); s += __shfl_xor(s, 8, 64);
    t += __shfl_xor(t, 1, 64); t += __shfl_xor(t, 2, 64);
    t += __shfl_xor(t, 4, 64); t += __shfl_xor(t, 8, 64);
    if (ok && col16 == 0){ as_[rr] = s; ad_[rr] = t; }
  }
}

// ============ layer-2 per-dst gather (H=1, C=40), MLP-4 + fused bias+log_softmax ============
__global__ __launch_bounds__(256) void k_gat2(const unsigned* __restrict__ off_, const unsigned* __restrict__ cur,
    const int* __restrict__ srcids, const float* __restrict__ as_, const float* __restrict__ ad_,
    const unsigned short* __restrict__ h2b, const float* __restrict__ b2, float* __restrict__ out, int N){
  int lane = threadIdx.x & 63;
  int wv   = threadIdx.x >> 6;
  int d    = blockIdx.x * 4 + wv;
  if (d >= N) return;
  __shared__ float lds_p[4][64];
  __shared__ int   lds_s[4][64];
  float* lp = lds_p[wv];
  int*   ls = lds_s[wv];
  unsigned beg = off_[d], fin = cur[d];
  float add = ad_[d];

  int c0 = lane & 31;
  int pe = lane >> 5;
  int idx = c0 < 20 ? c0 : 19;
  float ps = 0.f, accx = 0.f, accy = 0.f;

  for (unsigned base = beg; base < fin; base += 64){
    unsigned i = base + lane;
    int nthis = (int)min(64u, fin - base);
    if (i < fin){
      int s = srcids[i];
      float p = __expf(lrelu(as_[s] + add));
      ps += p; ls[lane] = s; lp[lane] = p;
    } else { ls[lane] = 0; lp[lane] = 0.f; }
    asm volatile("s_waitcnt lgkmcnt(0)" ::: "memory");
    __builtin_amdgcn_sched_barrier(0);
    for (int e = 0; e < nthis; e += 8){
      int e0 = e + pe, e1 = e + 2 + pe, e2 = e + 4 + pe, e3 = e + 6 + pe;
      float p0 = lp[e0], p1 = lp[e1], p2 = lp[e2], p3 = lp[e3];
      int s0 = ls[e0], s1 = ls[e1], s2 = ls[e2], s3 = ls[e3];
      unsigned u0 = *(const unsigned*)(h2b + (size_t)s0 * 40 + idx * 2);
      unsigned u1 = *(const unsigned*)(h2b + (size_t)s1 * 40 + idx * 2);
      unsigned u2 = *(const unsigned*)(h2b + (size_t)s2 * 40 + idx * 2);
      unsigned u3 = *(const unsigned*)(h2b + (size_t)s3 * 40 + idx * 2);
      accx = fmaf(p0, __uint_as_float(u0 << 16), accx);
      accy = fmaf(p0, __uint_as_float(u0 & 0xFFFF0000u), accy);
      accx = fmaf(p1, __uint_as_float(u1 << 16), accx);
      accy = fmaf(p1, __uint_as_float(u1 & 0xFFFF0000u), accy);
      accx = fmaf(p2, __uint_as_float(u2 << 16), accx);
      accy = fmaf(p2, __uint_as_float(u2 & 0xFFFF0000u), accy);
      accx = fmaf(p3, __uint_as_float(u3 << 16), accx);
      accy = fmaf(p3, __uint_as_float(u3 & 0xFFFF0000u), accy);
    }
    asm volatile("" ::: "memory");
  }
  ps = wred_sum(ps);
  accx += __shfl_xor(accx, 32, 64);
  accy += __shfl_xor(accy, 32, 64);

  float v0 = accx / ps + b2[idx * 2];
  float v1 = accy / ps + b2[idx * 2 + 1];
  bool act = (c0 < 20);
  float mx = act ? fmaxf(v0, v1) : -INFINITY;
  #pragma unroll
  for (int o = 16; o; o >>= 1) mx = fmaxf(mx, __shfl_xor(mx, o, 64));
  float exs = act ? (__expf(v0 - mx) + __expf(v1 - mx)) : 0.f;
  #pragma unroll
  for (int o = 16; o; o >>= 1) exs += __shfl_xor(exs, o, 64);
  float lse = mx + logf(exs);
  if (lane < 20){
    float2 o2; o2.x = v0 - lse; o2.y = v1 - lse;
    *(float2*)(out + (size_t)d * 40 + lane * 2) = o2;
  }
}

extern "C" void kernel_launch(void* const* d_in, const int* in_sizes, int n_in,
                              void* d_out, int out_size, void* d_ws, size_t ws_size,
                              hipStream_t stream){
  const float* x   = (const float*)d_in[0];
  const int*   ei  = (const int*)d_in[1];
  const float* W1  = (const float*)d_in[2];
  const float* a1s = (const float*)d_in[3];
  const float* a1d = (const float*)d_in[4];
  const float* b1  = (const float*)d_in[5];
  const float* W2  = (const float*)d_in[6];
  const float* a2s = (const float*)d_in[7];
  const float* a2d = (const float*)d_in[8];
  const float* b2  = (const float*)d_in[9];
  float* out = (float*)d_out;

  const int N = in_sizes[0] / 256;
  const int E = in_sizes[1] / 2;
  const int tot = E + N;
  const int nb  = (N + 255) >> 8;

  float* ws = (float*)d_ws;
  size_t o = 0;
  float* as1  = ws + o; o += (size_t)N * 8;
  float* ad1  = ws + o; o += (size_t)N * 8;
  unsigned short* out1b = (unsigned short*)(ws + o); o += (size_t)N * 32;  // aliases `staged`
  unsigned short* h1b   = (unsigned short*)(ws + o); o += (size_t)N * 32;
  unsigned short* h2b   = (unsigned short*)(ws + o); o += (size_t)N * 20;
  unsigned* off_ = (unsigned*)(ws + o); o += (size_t)N;
  unsigned* cur  = (unsigned*)(ws + o); o += (size_t)N;
  int* srcids    = (int*)(ws + o);      o += (size_t)tot;
  short* wt_hi   = (short*)(ws + o);    o += 8192;   // 16384 bf16
  short* wt_lo   = (short*)(ws + o);    o += 8192;
  short* wt2_hi  = (short*)(ws + o);    o += 1536;   // 3072 bf16 (48x64)
  short* wt2_lo  = (short*)(ws + o);    o += 1536;
  unsigned* bcnt  = (unsigned*)(ws + o); o += nb;
  unsigned* bbase = (unsigned*)(ws + o); o += nb + 1;
  unsigned* bcur  = (unsigned*)(ws + o); o += nb;
  unsigned* staged = (unsigned*)out1b;
  float* as2 = as1;
  float* ad2 = ad1;

  const int cb = (tot + 8191) / 8192;

  hipMemsetAsync(bcnt, 0, sizeof(unsigned) * (size_t)nb, stream);

  // bucketed CSR build
  k_bincnt <<<cb, 256, 0, stream>>>(ei, E, N, nb, bcnt);
  k_bscan  <<<1, 512, 0, stream>>>(bcnt, bbase, bcur, nb, tot);
  k_binscat<<<cb, 256, 0, stream>>>(ei, E, N, nb, bcur, staged);
  k_csr    <<<nb, 256, 0, stream>>>(bbase, staged, N, off_, cur, srcids);

  // weight prep
  k_wprep <<<64, 256, 0, stream>>>(W1, wt_hi, wt_lo);
  k_w2prep<<<12, 256, 0, stream>>>(W2, wt2_hi, wt2_lo);

  // layer 1
  k_gemm1_mfma<<<(N + 63) / 64, 256, 0, stream>>>(x, wt_hi, wt_lo, a1s, a1d, h1b, as1, ad1, N);
  k_gat1 <<<(N + 3) / 4, 256, 0, stream>>>(off_, cur, srcids, as1, ad1, h1b, b1, out1b, N);

  // layer 2
  k_gemm2m<<<(N + 63) / 64, 256, 0, stream>>>(out1b, wt2_hi, wt2_lo, a2s, a2d, h2b, as2, ad2, N);
  k_gat2  <<<(N + 3) / 4, 256, 0, stream>>>(off_, cur, srcids, as2, ad2, h2b, b2, out, N);
}

// Round 15
// 234.847 us; speedup vs baseline: 1.1240x; 1.1240x over previous
//
#include <hip/hip_runtime.h>
#include <math.h>

#define NEG_SLOPE 0.2f
__device__ __forceinline__ float lrelu(float x){ return x >= 0.f ? x : NEG_SLOPE * x; }

typedef __attribute__((ext_vector_type(8))) short bf16x8;
typedef __attribute__((ext_vector_type(4))) float f32x4;

__device__ __forceinline__ float wred_sum(float v){
  #pragma unroll
  for (int o = 32; o; o >>= 1) v += __shfl_xor(v, o, 64);
  return v;
}

__device__ __forceinline__ float bfhi_f(float f){
  return __uint_as_float(__float_as_uint(f) & 0xFFFF0000u);
}
// fp32 -> bf16 RTNE
__device__ __forceinline__ unsigned short f2bf(float f){
  unsigned u = __float_as_uint(f);
  unsigned r = u + 0x7FFFu + ((u >> 16) & 1u);
  return (unsigned short)(r >> 16);
}

// ================= bucketed CSR build =================
__global__ __launch_bounds__(256) void k_bincnt(const int* __restrict__ ei, int E, int N, int nb,
                                                unsigned* __restrict__ bcnt){
  __shared__ unsigned h[512];
  const int tot = E + N;
  for (int i = threadIdx.x; i < nb; i += 256) h[i] = 0;
  __syncthreads();
  int base = blockIdx.x * 8192;
  #pragma unroll 4
  for (int j = 0; j < 32; j++){
    int e = base + threadIdx.x + j * 256;
    if (e < tot){
      unsigned d = (e < E) ? (unsigned)ei[E + e] : (unsigned)(e - E);
      atomicAdd(&h[d >> 8], 1u);
    }
  }
  __syncthreads();
  for (int i = threadIdx.x; i < nb; i += 256)
    if (h[i]) atomicAdd(&bcnt[i], h[i]);
}

__global__ void k_bscan(const unsigned* __restrict__ bcnt, unsigned* __restrict__ bbase,
                        unsigned* __restrict__ bcur, int nb, int tot){
  __shared__ unsigned s[512];
  int t = threadIdx.x;
  unsigned v = (t < nb) ? bcnt[t] : 0u;
  s[t] = v; __syncthreads();
  for (int off = 1; off < 512; off <<= 1){
    unsigned x = (t >= off) ? s[t - off] : 0u; __syncthreads();
    s[t] += x; __syncthreads();
  }
  if (t < nb){ unsigned b = s[t] - v; bbase[t] = b; bcur[t] = b; }
  if (t == 0) bbase[nb] = (unsigned)tot;
}

__global__ __launch_bounds__(256) void k_binscat(const int* __restrict__ ei, int E, int N, int nb,
    unsigned* __restrict__ bcur, unsigned* __restrict__ staged){
  __shared__ unsigned sd[8192];
  __shared__ unsigned hist[512];
  __shared__ unsigned runb[512];
  const int tot = E + N;
  for (int i = threadIdx.x; i < nb; i += 256) hist[i] = 0;
  __syncthreads();
  int base = blockIdx.x * 8192;
  #pragma unroll 4
  for (int j = 0; j < 32; j++){
    int idx = threadIdx.x + j * 256;
    int e = base + idx;
    unsigned d = 0xFFFFFFFFu;
    if (e < tot) d = (e < E) ? (unsigned)ei[E + e] : (unsigned)(e - E);
    sd[idx] = d;
    if (d != 0xFFFFFFFFu) atomicAdd(&hist[d >> 8], 1u);
  }
  __syncthreads();
  for (int i = threadIdx.x; i < nb; i += 256){
    unsigned c = hist[i];
    runb[i] = c ? atomicAdd(&bcur[i], c) : 0u;
    hist[i] = 0;
  }
  __syncthreads();
  #pragma unroll 4
  for (int j = 0; j < 32; j++){
    int idx = threadIdx.x + j * 256;
    unsigned d = sd[idx];
    if (d == 0xFFFFFFFFu) continue;
    int e = base + idx;
    unsigned s = (e < E) ? (unsigned)ei[e] : d;
    unsigned b = d >> 8;
    unsigned pos = runb[b] + atomicAdd(&hist[b], 1u);
    staged[pos] = s | ((d & 255u) << 20);
  }
}

__global__ __launch_bounds__(256) void k_csr(const unsigned* __restrict__ bbase,
    const unsigned* __restrict__ staged, int N,
    unsigned* __restrict__ off_, unsigned* __restrict__ cur, int* __restrict__ srcids){
  __shared__ unsigned cnt[256], scn[256], cnt2[256];
  int b = blockIdx.x, t = threadIdx.x;
  unsigned beg = bbase[b], end = bbase[b + 1];
  cnt[t] = 0; cnt2[t] = 0;
  __syncthreads();
  for (unsigned i = beg + t; i < end; i += 256)
    atomicAdd(&cnt[staged[i] >> 20], 1u);
  __syncthreads();
  unsigned v = cnt[t];
  scn[t] = v; __syncthreads();
  for (int off = 1; off < 256; off <<= 1){
    unsigned x = (t >= off) ? scn[t - off] : 0u; __syncthreads();
    scn[t] += x; __syncthreads();
  }
  unsigned ex = scn[t] - v;
  int d = b * 256 + t;
  if (d < N){ off_[d] = beg + ex; cur[d] = beg + ex + v; }
  cnt[t] = ex;
  __syncthreads();
  for (unsigned i = beg + t; i < end; i += 256){
    unsigned u = staged[i];
    unsigned dl = u >> 20;
    unsigned pos = beg + cnt[dl] + atomicAdd(&cnt2[dl], 1u);
    srcids[pos] = (int)(u & 0xFFFFFu);
  }
}

// ============ W1 prep: Wt_hi/Wt_lo[64][256] bf16 ============
__global__ void k_wprep(const float* __restrict__ W, short* __restrict__ wt_hi,
                        short* __restrict__ wt_lo){
  int i = blockIdx.x * 256 + threadIdx.x;    // 16384
  int k = i >> 6, c = i & 63;
  float v = W[i];
  unsigned u = __float_as_uint(v);
  wt_hi[c * 256 + k] = (short)(u >> 16);
  float lo = v - bfhi_f(v);
  wt_lo[c * 256 + k] = (short)(__float_as_uint(lo) >> 16);
}

// ============ W2 prep: [48][64] bf16 hi/lo (cols 40-47 zero) ============
__global__ void k_w2prep(const float* __restrict__ W2, short* __restrict__ hi,
                         short* __restrict__ lo){
  int i = blockIdx.x * 256 + threadIdx.x;    // 3072
  if (i >= 48 * 64) return;
  int c = i >> 6, k = i & 63;
  float v = (c < 40) ? W2[k * 40 + c] : 0.f;
  unsigned u = __float_as_uint(v);
  hi[c * 64 + k] = (short)(u >> 16);
  float l = v - bfhi_f(v);
  lo[c * 64 + k] = (short)(__float_as_uint(l) >> 16);
}

// ============ GEMM1 via MFMA: R8 structure + B tables staged in LDS ============
// Diagnosis across R9-R14: throughput wall independent of TLP/MLP/HBM/VALU/MFMA
// -> TA address-rate bound. B-table loads are 64 of 98 VMEM instrs per wave
// (every wave re-reads the same 64KB through the TA). Staging B in LDS removes
// them from the TA path: 98 -> 34 VMEM instrs/wave. Row padding +4 u32 (132
// stride) -> 2-way bank aliasing on ds_read_b128 (free, m136).
__global__ __launch_bounds__(256) void k_gemm1_mfma(const float* __restrict__ x,
    const unsigned* __restrict__ wtu_hi, const unsigned* __restrict__ wtu_lo,
    const float* __restrict__ a1s, const float* __restrict__ a1d,
    unsigned short* __restrict__ h1b, float* __restrict__ as_, float* __restrict__ ad_, int N){
  __shared__ unsigned ldsB[2][64 * 132];     // [hi|lo][64 rows x 132 u32 (128 data + 4 pad)]
  int lane = threadIdx.x & 63;
  int wv   = threadIdx.x >> 6;
  int r0   = blockIdx.x * 64 + wv * 16;
  int col16 = lane & 15;
  int kg    = lane >> 4;

  // cooperative stage: 8192 u32 per table, coalesced reads, linear->padded writes
  #pragma unroll
  for (int j = 0; j < 32; j++){
    int g = threadIdx.x + j * 256;
    int row = g >> 7, col = g & 127;
    ldsB[0][row * 132 + col] = wtu_hi[g];
    ldsB[1][row * 132 + col] = wtu_lo[g];
  }
  __syncthreads();
  if (r0 >= N) return;

  const float* xr = x + (size_t)min(r0 + col16, N - 1) * 256 + kg * 8;

  f32x4 acc[4];
  #pragma unroll
  for (int ct = 0; ct < 4; ct++) acc[ct] = (f32x4){0.f, 0.f, 0.f, 0.f};

  #pragma unroll 2
  for (int kt = 0; kt < 8; kt++){
    float4 v0 = *(const float4*)(xr + kt * 32);
    float4 v1 = *(const float4*)(xr + kt * 32 + 4);
    unsigned u[8] = {__float_as_uint(v0.x), __float_as_uint(v0.y), __float_as_uint(v0.z), __float_as_uint(v0.w),
                     __float_as_uint(v1.x), __float_as_uint(v1.y), __float_as_uint(v1.z), __float_as_uint(v1.w)};
    union { bf16x8 v; unsigned u[4]; } ahi, alo;
    #pragma unroll
    for (int j = 0; j < 4; j++)
      ahi.u[j] = __builtin_amdgcn_perm(u[2*j+1], u[2*j], 0x07060302);
    float lo[8];
    lo[0] = v0.x - bfhi_f(v0.x); lo[1] = v0.y - bfhi_f(v0.y);
    lo[2] = v0.z - bfhi_f(v0.z); lo[3] = v0.w - bfhi_f(v0.w);
    lo[4] = v1.x - bfhi_f(v1.x); lo[5] = v1.y - bfhi_f(v1.y);
    lo[6] = v1.z - bfhi_f(v1.z); lo[7] = v1.w - bfhi_f(v1.w);
    #pragma unroll
    for (int j = 0; j < 4; j++)
      alo.u[j] = __builtin_amdgcn_perm(__float_as_uint(lo[2*j+1]), __float_as_uint(lo[2*j]), 0x07060302);

    #pragma unroll
    for (int ct = 0; ct < 4; ct++){
      int wcol = ct * 16 + col16;
      const bf16x8 bhi = *(const bf16x8*)(&ldsB[0][wcol * 132 + kt * 16 + kg * 4]);
      const bf16x8 blo = *(const bf16x8*)(&ldsB[1][wcol * 132 + kt * 16 + kg * 4]);
      acc[ct] = __builtin_amdgcn_mfma_f32_16x16x32_bf16(ahi.v, bhi, acc[ct], 0, 0, 0);
      acc[ct] = __builtin_amdgcn_mfma_f32_16x16x32_bf16(ahi.v, blo, acc[ct], 0, 0, 0);
      acc[ct] = __builtin_amdgcn_mfma_f32_16x16x32_bf16(alo.v, bhi, acc[ct], 0, 0, 0);
    }
  }

  float cs[4], cd[4];
  #pragma unroll
  for (int ct = 0; ct < 4; ct++){ cs[ct] = a1s[ct * 16 + col16]; cd[ct] = a1d[ct * 16 + col16]; }
  #pragma unroll
  for (int r = 0; r < 4; r++){
    int rr = r0 + kg * 4 + r;
    bool ok = rr < N;
    #pragma unroll
    for (int ct = 0; ct < 4; ct++){
      float v = acc[ct][r];
      if (ok) h1b[(size_t)rr * 64 + ct * 16 + col16] = f2bf(v);
      float s = v * cs[ct];
      float t = v * cd[ct];
      s += __shfl_xor(s, 1, 64); s += __shfl_xor(s, 2, 64); s += __shfl_xor(s, 4, 64);
      t += __shfl_xor(t, 1, 64); t += __shfl_xor(t, 2, 64); t += __shfl_xor(t, 4, 64);
      if (ok && (col16 & 7) == 0){
        int head = ct * 2 + (col16 >> 3);
        as_[(size_t)rr * 8 + head] = s;
        ad_[(size_t)rr * 8 + head] = t;
      }
    }
  }
}

// ============ layer-1 per-dst gather: staged srcids, MLP-4 channel phase ============
__global__ __launch_bounds__(256) void k_gat1(const unsigned* __restrict__ off_, const unsigned* __restrict__ cur,
    const int* __restrict__ srcids, const float* __restrict__ as_, const float* __restrict__ ad_,
    const unsigned short* __restrict__ h1b, const float* __restrict__ b1,
    unsigned short* __restrict__ out1b, int N){
  int lane = threadIdx.x & 63;
  int wv   = threadIdx.x >> 6;
  int d    = blockIdx.x * 4 + wv;
  if (d >= N) return;
  __shared__ float lds_p[4][64 * 8];
  __shared__ int   lds_s[4][64];
  float* lp = lds_p[wv];
  int*   ls = lds_s[wv];
  unsigned beg = off_[d], fin = cur[d];

  int e8 = lane >> 3, h = lane & 7;                  // exp-phase layout
  int c0 = lane & 31, pe = lane >> 5, hh = c0 >> 2;  // channel-phase layout
  float adh = ad_[(size_t)d * 8 + h];
  float psacc = 0.f, accx = 0.f, accy = 0.f;

  for (unsigned base = beg; base < fin; base += 64){
    int nthis = (int)min(64u, fin - base);
    unsigned i = base + lane;
    ls[lane] = (i < fin) ? srcids[i] : 0;            // one coalesced stage
    asm volatile("s_waitcnt lgkmcnt(0)" ::: "memory");
    __builtin_amdgcn_sched_barrier(0);
    for (int j = 0; j < nthis; j += 8){
      int eloc = j + e8;
      int s = ls[eloc];
      float p = 0.f;
      if (eloc < nthis) p = __expf(lrelu(as_[(size_t)s * 8 + h] + adh));
      lp[eloc * 8 + h] = p;
      psacc += p;
    }
    asm volatile("s_waitcnt lgkmcnt(0)" ::: "memory");
    __builtin_amdgcn_sched_barrier(0);
    for (int e = 0; e < nthis; e += 8){
      int e0 = e + pe, e1 = e + 2 + pe, e2 = e + 4 + pe, e3 = e + 6 + pe;
      float p0 = lp[e0 * 8 + hh], p1 = lp[e1 * 8 + hh];
      float p2 = lp[e2 * 8 + hh], p3 = lp[e3 * 8 + hh];
      int s0 = ls[e0], s1 = ls[e1], s2 = ls[e2], s3 = ls[e3];
      unsigned u0 = *(const unsigned*)(h1b + (size_t)s0 * 64 + c0 * 2);
      unsigned u1 = *(const unsigned*)(h1b + (size_t)s1 * 64 + c0 * 2);
      unsigned u2 = *(const unsigned*)(h1b + (size_t)s2 * 64 + c0 * 2);
      unsigned u3 = *(const unsigned*)(h1b + (size_t)s3 * 64 + c0 * 2);
      accx = fmaf(p0, __uint_as_float(u0 << 16), accx);
      accy = fmaf(p0, __uint_as_float(u0 & 0xFFFF0000u), accy);
      accx = fmaf(p1, __uint_as_float(u1 << 16), accx);
      accy = fmaf(p1, __uint_as_float(u1 & 0xFFFF0000u), accy);
      accx = fmaf(p2, __uint_as_float(u2 << 16), accx);
      accy = fmaf(p2, __uint_as_float(u2 & 0xFFFF0000u), accy);
      accx = fmaf(p3, __uint_as_float(u3 << 16), accx);
      accy = fmaf(p3, __uint_as_float(u3 & 0xFFFF0000u), accy);
    }
    asm volatile("" ::: "memory");
  }
  float den = psacc;
  den += __shfl_xor(den, 8, 64);
  den += __shfl_xor(den, 16, 64);
  den += __shfl_xor(den, 32, 64);
  float mydenv = __shfl(den, hh, 64);
  accx += __shfl_xor(accx, 32, 64);
  accy += __shfl_xor(accy, 32, 64);
  if (lane < 32){
    int ch = lane * 2;
    float v0 = accx / mydenv + b1[ch];
    float v1 = accy / mydenv + b1[ch + 1];
    ushort2 o;
    o.x = f2bf(v0 > 0.f ? v0 : 0.f);
    o.y = f2bf(v1 > 0.f ? v1 : 0.f);
    *(ushort2*)(out1b + (size_t)d * 64 + ch) = o;
  }
}

// ============ GEMM2 via MFMA (bf16 A, hi/lo B) + fused alpha2 ============
__global__ __launch_bounds__(256) void k_gemm2m(const unsigned short* __restrict__ out1b,
    const short* __restrict__ wt2_hi, const short* __restrict__ wt2_lo,
    const float* __restrict__ a2s, const float* __restrict__ a2d,
    unsigned short* __restrict__ h2b, float* __restrict__ as_, float* __restrict__ ad_, int N){
  int lane = threadIdx.x & 63;
  int wv   = threadIdx.x >> 6;
  int r0   = blockIdx.x * 64 + wv * 16;
  if (r0 >= N) return;
  int col16 = lane & 15;
  int kg    = lane >> 4;
  const unsigned short* ar = out1b + (size_t)min(r0 + col16, N - 1) * 64 + kg * 8;

  f32x4 acc[3];
  #pragma unroll
  for (int ct = 0; ct < 3; ct++) acc[ct] = (f32x4){0.f, 0.f, 0.f, 0.f};

  #pragma unroll
  for (int kt = 0; kt < 2; kt++){
    const bf16x8 a = *(const bf16x8*)(ar + kt * 32);
    #pragma unroll
    for (int ct = 0; ct < 3; ct++){
      int wcol = ct * 16 + col16;
      const bf16x8 bhi = *(const bf16x8*)(wt2_hi + wcol * 64 + kt * 32 + kg * 8);
      const bf16x8 blo = *(const bf16x8*)(wt2_lo + wcol * 64 + kt * 32 + kg * 8);
      acc[ct] = __builtin_amdgcn_mfma_f32_16x16x32_bf16(a, bhi, acc[ct], 0, 0, 0);
      acc[ct] = __builtin_amdgcn_mfma_f32_16x16x32_bf16(a, blo, acc[ct], 0, 0, 0);
    }
  }

  float cs[3], cd[3];
  #pragma unroll
  for (int ct = 0; ct < 3; ct++){
    int col = ct * 16 + col16;
    bool okc = col < 40;
    cs[ct] = okc ? a2s[col] : 0.f;
    cd[ct] = okc ? a2d[col] : 0.f;
  }
  #pragma unroll
  for (int r = 0; r < 4; r++){
    int rr = r0 + kg * 4 + r;
    bool ok = rr < N;
    float s = 0.f, t = 0.f;
    #pragma unroll
    for (int ct = 0; ct < 3; ct++){
      s = fmaf(acc[ct][r], cs[ct], s);
      t = fmaf(acc[ct][r], cd[ct], t);
      int col = ct * 16 + col16;
      if (ok && col < 40) h2b[(size_t)rr * 40 + col] = f2bf(acc[ct][r]);
    }
    s += __shfl_xor(s, 1, 64); s += __shfl_xor(s, 2, 64);
    s += __shfl_xor(s, 4, 64); s += __shfl_xor(s, 8, 64);
    t += __shfl_xor(t, 1, 64); t += __shfl_xor(t, 2, 64);
    t += __shfl_xor(t, 4, 64); t += __shfl_xor(t, 8, 64);
    if (ok && col16 == 0){ as_[rr] = s; ad_[rr] = t; }
  }
}

// ============ layer-2 per-dst gather (H=1, C=40), MLP-4 + fused bias+log_softmax ============
__global__ __launch_bounds__(256) void k_gat2(const unsigned* __restrict__ off_, const unsigned* __restrict__ cur,
    const int* __restrict__ srcids, const float* __restrict__ as_, const float* __restrict__ ad_,
    const unsigned short* __restrict__ h2b, const float* __restrict__ b2, float* __restrict__ out, int N){
  int lane = threadIdx.x & 63;
  int wv   = threadIdx.x >> 6;
  int d    = blockIdx.x * 4 + wv;
  if (d >= N) return;
  __shared__ float lds_p[4][64];
  __shared__ int   lds_s[4][64];
  float* lp = lds_p[wv];
  int*   ls = lds_s[wv];
  unsigned beg = off_[d], fin = cur[d];
  float add = ad_[d];

  int c0 = lane & 31;
  int pe = lane >> 5;
  int idx = c0 < 20 ? c0 : 19;
  float ps = 0.f, accx = 0.f, accy = 0.f;

  for (unsigned base = beg; base < fin; base += 64){
    unsigned i = base + lane;
    int nthis = (int)min(64u, fin - base);
    if (i < fin){
      int s = srcids[i];
      float p = __expf(lrelu(as_[s] + add));
      ps += p; ls[lane] = s; lp[lane] = p;
    } else { ls[lane] = 0; lp[lane] = 0.f; }
    asm volatile("s_waitcnt lgkmcnt(0)" ::: "memory");
    __builtin_amdgcn_sched_barrier(0);
    for (int e = 0; e < nthis; e += 8){
      int e0 = e + pe, e1 = e + 2 + pe, e2 = e + 4 + pe, e3 = e + 6 + pe;
      float p0 = lp[e0], p1 = lp[e1], p2 = lp[e2], p3 = lp[e3];
      int s0 = ls[e0], s1 = ls[e1], s2 = ls[e2], s3 = ls[e3];
      unsigned u0 = *(const unsigned*)(h2b + (size_t)s0 * 40 + idx * 2);
      unsigned u1 = *(const unsigned*)(h2b + (size_t)s1 * 40 + idx * 2);
      unsigned u2 = *(const unsigned*)(h2b + (size_t)s2 * 40 + idx * 2);
      unsigned u3 = *(const unsigned*)(h2b + (size_t)s3 * 40 + idx * 2);
      accx = fmaf(p0, __uint_as_float(u0 << 16), accx);
      accy = fmaf(p0, __uint_as_float(u0 & 0xFFFF0000u), accy);
      accx = fmaf(p1, __uint_as_float(u1 << 16), accx);
      accy = fmaf(p1, __uint_as_float(u1 & 0xFFFF0000u), accy);
      accx = fmaf(p2, __uint_as_float(u2 << 16), accx);
      accy = fmaf(p2, __uint_as_float(u2 & 0xFFFF0000u), accy);
      accx = fmaf(p3, __uint_as_float(u3 << 16), accx);
      accy = fmaf(p3, __uint_as_float(u3 & 0xFFFF0000u), accy);
    }
    asm volatile("" ::: "memory");
  }
  ps = wred_sum(ps);
  accx += __shfl_xor(accx, 32, 64);
  accy += __shfl_xor(accy, 32, 64);

  float v0 = accx / ps + b2[idx * 2];
  float v1 = accy / ps + b2[idx * 2 + 1];
  bool act = (c0 < 20);
  float mx = act ? fmaxf(v0, v1) : -INFINITY;
  #pragma unroll
  for (int o = 16; o; o >>= 1) mx = fmaxf(mx, __shfl_xor(mx, o, 64));
  float exs = act ? (__expf(v0 - mx) + __expf(v1 - mx)) : 0.f;
  #pragma unroll
  for (int o = 16; o; o >>= 1) exs += __shfl_xor(exs, o, 64);
  float lse = mx + logf(exs);
  if (lane < 20){
    float2 o2; o2.x = v0 - lse; o2.y = v1 - lse;
    *(float2*)(out + (size_t)d * 40 + lane * 2) = o2;
  }
}

extern "C" void kernel_launch(void* const* d_in, const int* in_sizes, int n_in,
                              void* d_out, int out_size, void* d_ws, size_t ws_size,
                              hipStream_t stream){
  const float* x   = (const float*)d_in[0];
  const int*   ei  = (const int*)d_in[1];
  const float* W1  = (const float*)d_in[2];
  const float* a1s = (const float*)d_in[3];
  const float* a1d = (const float*)d_in[4];
  const float* b1  = (const float*)d_in[5];
  const float* W2  = (const float*)d_in[6];
  const float* a2s = (const float*)d_in[7];
  const float* a2d = (const float*)d_in[8];
  const float* b2  = (const float*)d_in[9];
  float* out = (float*)d_out;

  const int N = in_sizes[0] / 256;
  const int E = in_sizes[1] / 2;
  const int tot = E + N;
  const int nb  = (N + 255) >> 8;

  float* ws = (float*)d_ws;
  size_t o = 0;
  float* as1  = ws + o; o += (size_t)N * 8;
  float* ad1  = ws + o; o += (size_t)N * 8;
  unsigned short* out1b = (unsigned short*)(ws + o); o += (size_t)N * 32;  // aliases `staged`
  unsigned short* h1b   = (unsigned short*)(ws + o); o += (size_t)N * 32;
  unsigned short* h2b   = (unsigned short*)(ws + o); o += (size_t)N * 20;
  unsigned* off_ = (unsigned*)(ws + o); o += (size_t)N;
  unsigned* cur  = (unsigned*)(ws + o); o += (size_t)N;
  int* srcids    = (int*)(ws + o);      o += (size_t)tot;
  short* wt_hi   = (short*)(ws + o);    o += 8192;   // 16384 bf16
  short* wt_lo   = (short*)(ws + o);    o += 8192;
  short* wt2_hi  = (short*)(ws + o);    o += 1536;   // 3072 bf16 (48x64)
  short* wt2_lo  = (short*)(ws + o);    o += 1536;
  unsigned* bcnt  = (unsigned*)(ws + o); o += nb;
  unsigned* bbase = (unsigned*)(ws + o); o += nb + 1;
  unsigned* bcur  = (unsigned*)(ws + o); o += nb;
  unsigned* staged = (unsigned*)out1b;
  float* as2 = as1;
  float* ad2 = ad1;

  const int cb = (tot + 8191) / 8192;

  hipMemsetAsync(bcnt, 0, sizeof(unsigned) * (size_t)nb, stream);

  // bucketed CSR build
  k_bincnt <<<cb, 256, 0, stream>>>(ei, E, N, nb, bcnt);
  k_bscan  <<<1, 512, 0, stream>>>(bcnt, bbase, bcur, nb, tot);
  k_binscat<<<cb, 256, 0, stream>>>(ei, E, N, nb, bcur, staged);
  k_csr    <<<nb, 256, 0, stream>>>(bbase, staged, N, off_, cur, srcids);

  // weight prep
  k_wprep <<<64, 256, 0, stream>>>(W1, wt_hi, wt_lo);
  k_w2prep<<<12, 256, 0, stream>>>(W2, wt2_hi, wt2_lo);

  // layer 1
  k_gemm1_mfma<<<(N + 63) / 64, 256, 0, stream>>>(x, (const unsigned*)wt_hi, (const unsigned*)wt_lo,
                                                  a1s, a1d, h1b, as1, ad1, N);
  k_gat1 <<<(N + 3) / 4, 256, 0, stream>>>(off_, cur, srcids, as1, ad1, h1b, b1, out1b, N);

  // layer 2
  k_gemm2m<<<(N + 63) / 64, 256, 0, stream>>>(out1b, wt2_hi, wt2_lo, a2s, a2d, h2b, as2, ad2, N);
  k_gat2  <<<(N + 3) / 4, 256, 0, stream>>>(off_, cur, srcids, as2, ad2, h2b, b2, out, N);
}

// Round 16
// 234.144 us; speedup vs baseline: 1.1273x; 1.0030x over previous
//
#include <hip/hip_runtime.h>
#include <math.h>

#define NEG_SLOPE 0.2f
__device__ __forceinline__ float lrelu(float x){ return x >= 0.f ? x : NEG_SLOPE * x; }

typedef __attribute__((ext_vector_type(8))) short bf16x8;
typedef __attribute__((ext_vector_type(4))) float f32x4;

__device__ __forceinline__ float wred_sum(float v){
  #pragma unroll
  for (int o = 32; o; o >>= 1) v += __shfl_xor(v, o, 64);
  return v;
}

__device__ __forceinline__ float bfhi_f(float f){
  return __uint_as_float(__float_as_uint(f) & 0xFFFF0000u);
}
// fp32 -> bf16 RTNE
__device__ __forceinline__ unsigned short f2bf(float f){
  unsigned u = __float_as_uint(f);
  unsigned r = u + 0x7FFFu + ((u >> 16) & 1u);
  return (unsigned short)(r >> 16);
}

// split a 8-float row chunk into hi/lo bf16x8 fragments
__device__ __forceinline__ void cvt_hilo(float4 v0, float4 v1, bf16x8* hi, bf16x8* lo){
  unsigned u[8] = {__float_as_uint(v0.x), __float_as_uint(v0.y), __float_as_uint(v0.z), __float_as_uint(v0.w),
                   __float_as_uint(v1.x), __float_as_uint(v1.y), __float_as_uint(v1.z), __float_as_uint(v1.w)};
  union { bf16x8 v; unsigned u[4]; } H, L;
  #pragma unroll
  for (int j = 0; j < 4; j++)
    H.u[j] = __builtin_amdgcn_perm(u[2*j+1], u[2*j], 0x07060302);
  float l[8];
  l[0] = v0.x - bfhi_f(v0.x); l[1] = v0.y - bfhi_f(v0.y);
  l[2] = v0.z - bfhi_f(v0.z); l[3] = v0.w - bfhi_f(v0.w);
  l[4] = v1.x - bfhi_f(v1.x); l[5] = v1.y - bfhi_f(v1.y);
  l[6] = v1.z - bfhi_f(v1.z); l[7] = v1.w - bfhi_f(v1.w);
  #pragma unroll
  for (int j = 0; j < 4; j++)
    L.u[j] = __builtin_amdgcn_perm(__float_as_uint(l[2*j+1]), __float_as_uint(l[2*j]), 0x07060302);
  *hi = H.v; *lo = L.v;
}

// ================= bucketed CSR build =================
__global__ __launch_bounds__(256) void k_bincnt(const int* __restrict__ ei, int E, int N, int nb,
                                                unsigned* __restrict__ bcnt){
  __shared__ unsigned h[512];
  const int tot = E + N;
  for (int i = threadIdx.x; i < nb; i += 256) h[i] = 0;
  __syncthreads();
  int base = blockIdx.x * 8192;
  #pragma unroll 4
  for (int j = 0; j < 32; j++){
    int e = base + threadIdx.x + j * 256;
    if (e < tot){
      unsigned d = (e < E) ? (unsigned)ei[E + e] : (unsigned)(e - E);
      atomicAdd(&h[d >> 8], 1u);
    }
  }
  __syncthreads();
  for (int i = threadIdx.x; i < nb; i += 256)
    if (h[i]) atomicAdd(&bcnt[i], h[i]);
}

__global__ void k_bscan(const unsigned* __restrict__ bcnt, unsigned* __restrict__ bbase,
                        unsigned* __restrict__ bcur, int nb, int tot){
  __shared__ unsigned s[512];
  int t = threadIdx.x;
  unsigned v = (t < nb) ? bcnt[t] : 0u;
  s[t] = v; __syncthreads();
  for (int off = 1; off < 512; off <<= 1){
    unsigned x = (t >= off) ? s[t - off] : 0u; __syncthreads();
    s[t] += x; __syncthreads();
  }
  if (t < nb){ unsigned b = s[t] - v; bbase[t] = b; bcur[t] = b; }
  if (t == 0) bbase[nb] = (unsigned)tot;
}

__global__ __launch_bounds__(256) void k_binscat(const int* __restrict__ ei, int E, int N, int nb,
    unsigned* __restrict__ bcur, unsigned* __restrict__ staged){
  __shared__ unsigned sd[8192];
  __shared__ unsigned hist[512];
  __shared__ unsigned runb[512];
  const int tot = E + N;
  for (int i = threadIdx.x; i < nb; i += 256) hist[i] = 0;
  __syncthreads();
  int base = blockIdx.x * 8192;
  #pragma unroll 4
  for (int j = 0; j < 32; j++){
    int idx = threadIdx.x + j * 256;
    int e = base + idx;
    unsigned d = 0xFFFFFFFFu;
    if (e < tot) d = (e < E) ? (unsigned)ei[E + e] : (unsigned)(e - E);
    sd[idx] = d;
    if (d != 0xFFFFFFFFu) atomicAdd(&hist[d >> 8], 1u);
  }
  __syncthreads();
  for (int i = threadIdx.x; i < nb; i += 256){
    unsigned c = hist[i];
    runb[i] = c ? atomicAdd(&bcur[i], c) : 0u;
    hist[i] = 0;
  }
  __syncthreads();
  #pragma unroll 4
  for (int j = 0; j < 32; j++){
    int idx = threadIdx.x + j * 256;
    unsigned d = sd[idx];
    if (d == 0xFFFFFFFFu) continue;
    int e = base + idx;
    unsigned s = (e < E) ? (unsigned)ei[e] : d;
    unsigned b = d >> 8;
    unsigned pos = runb[b] + atomicAdd(&hist[b], 1u);
    staged[pos] = s | ((d & 255u) << 20);
  }
}

__global__ __launch_bounds__(256) void k_csr(const unsigned* __restrict__ bbase,
    const unsigned* __restrict__ staged, int N,
    unsigned* __restrict__ off_, unsigned* __restrict__ cur, int* __restrict__ srcids){
  __shared__ unsigned cnt[256], scn[256], cnt2[256];
  int b = blockIdx.x, t = threadIdx.x;
  unsigned beg = bbase[b], end = bbase[b + 1];
  cnt[t] = 0; cnt2[t] = 0;
  __syncthreads();
  for (unsigned i = beg + t; i < end; i += 256)
    atomicAdd(&cnt[staged[i] >> 20], 1u);
  __syncthreads();
  unsigned v = cnt[t];
  scn[t] = v; __syncthreads();
  for (int off = 1; off < 256; off <<= 1){
    unsigned x = (t >= off) ? scn[t - off] : 0u; __syncthreads();
    scn[t] += x; __syncthreads();
  }
  unsigned ex = scn[t] - v;
  int d = b * 256 + t;
  if (d < N){ off_[d] = beg + ex; cur[d] = beg + ex + v; }
  cnt[t] = ex;
  __syncthreads();
  for (unsigned i = beg + t; i < end; i += 256){
    unsigned u = staged[i];
    unsigned dl = u >> 20;
    unsigned pos = beg + cnt[dl] + atomicAdd(&cnt2[dl], 1u);
    srcids[pos] = (int)(u & 0xFFFFFu);
  }
}

// ============ W1 prep: Wt_hi/Wt_lo[64][256] bf16 ============
__global__ void k_wprep(const float* __restrict__ W, short* __restrict__ wt_hi,
                        short* __restrict__ wt_lo){
  int i = blockIdx.x * 256 + threadIdx.x;    // 16384
  int k = i >> 6, c = i & 63;
  float v = W[i];
  unsigned u = __float_as_uint(v);
  wt_hi[c * 256 + k] = (short)(u >> 16);
  float lo = v - bfhi_f(v);
  wt_lo[c * 256 + k] = (short)(__float_as_uint(lo) >> 16);
}

// ============ W2 prep: [48][64] bf16 hi/lo (cols 40-47 zero) ============
__global__ void k_w2prep(const float* __restrict__ W2, short* __restrict__ hi,
                         short* __restrict__ lo){
  int i = blockIdx.x * 256 + threadIdx.x;    // 3072
  if (i >= 48 * 64) return;
  int c = i >> 6, k = i & 63;
  float v = (c < 40) ? W2[k * 40 + c] : 0.f;
  unsigned u = __float_as_uint(v);
  hi[c * 64 + k] = (short)(u >> 16);
  float l = v - bfhi_f(v);
  lo[c * 64 + k] = (short)(__float_as_uint(l) >> 16);
}

// shared epilogue for one 16-row tile
__device__ __forceinline__ void epi1(const f32x4* acc, int r0, int col16, int kg,
    const float* __restrict__ a1s, const float* __restrict__ a1d,
    unsigned short* __restrict__ h1b, float* __restrict__ as_, float* __restrict__ ad_, int N){
  float cs[4], cd[4];
  #pragma unroll
  for (int ct = 0; ct < 4; ct++){ cs[ct] = a1s[ct * 16 + col16]; cd[ct] = a1d[ct * 16 + col16]; }
  #pragma unroll
  for (int r = 0; r < 4; r++){
    int rr = r0 + kg * 4 + r;
    bool ok = rr < N;
    #pragma unroll
    for (int ct = 0; ct < 4; ct++){
      float v = acc[ct][r];
      if (ok) h1b[(size_t)rr * 64 + ct * 16 + col16] = f2bf(v);
      float s = v * cs[ct];
      float t = v * cd[ct];
      s += __shfl_xor(s, 1, 64); s += __shfl_xor(s, 2, 64); s += __shfl_xor(s, 4, 64);
      t += __shfl_xor(t, 1, 64); t += __shfl_xor(t, 2, 64); t += __shfl_xor(t, 4, 64);
      if (ok && (col16 & 7) == 0){
        int head = ct * 2 + (col16 >> 3);
        as_[(size_t)rr * 8 + head] = s;
        ad_[(size_t)rr * 8 + head] = t;
      }
    }
  }
}

// ============ GEMM1 via MFMA: BM=128, K-split LDS B staging (34.8KB -> 4 blk/CU) ============
// R15 proved B-in-LDS is the lever (TA address-rate). This round: (1) stage half
// of K at a time -> LDS 67.6->34.8KB, 2->4 blocks/CU; (2) each wave owns TWO
// 16-row tiles sharing B fragments -> half the blocks, half the total staging
// traffic, 2x independent x-loads per wave.
__global__ __launch_bounds__(256) void k_gemm1_mfma(const float* __restrict__ x,
    const unsigned* __restrict__ wtu_hi, const unsigned* __restrict__ wtu_lo,
    const float* __restrict__ a1s, const float* __restrict__ a1d,
    unsigned short* __restrict__ h1b, float* __restrict__ as_, float* __restrict__ ad_, int N){
  __shared__ unsigned ldsB[2][64 * 68];      // one K-half: 64 cols x (64 data + 4 pad) u32
  int lane = threadIdx.x & 63;
  int wv   = threadIdx.x >> 6;
  int col16 = lane & 15;
  int kg    = lane >> 4;
  int rA = blockIdx.x * 128 + wv * 16;
  int rB = rA + 64;
  const float* xA = x + (size_t)min(rA + col16, N - 1) * 256 + kg * 8;
  const float* xB = x + (size_t)min(rB + col16, N - 1) * 256 + kg * 8;

  f32x4 accA[4], accB[4];
  #pragma unroll
  for (int ct = 0; ct < 4; ct++){ accA[ct] = (f32x4){0.f,0.f,0.f,0.f}; accB[ct] = (f32x4){0.f,0.f,0.f,0.f}; }

  #pragma unroll
  for (int half = 0; half < 2; half++){
    // cooperative stage of this K-half (coalesced 256B row-chunks per wave)
    #pragma unroll
    for (int j = 0; j < 16; j++){
      int g = threadIdx.x + j * 256;         // 0..4095
      int row = g >> 6, col = g & 63;
      ldsB[0][row * 68 + col] = wtu_hi[row * 128 + half * 64 + col];
      ldsB[1][row * 68 + col] = wtu_lo[row * 128 + half * 64 + col];
    }
    __syncthreads();

    #pragma unroll
    for (int kt = 0; kt < 4; kt++){
      int xo = half * 128 + kt * 32;
      float4 a0 = *(const float4*)(xA + xo);
      float4 a1v = *(const float4*)(xA + xo + 4);
      float4 b0 = *(const float4*)(xB + xo);
      float4 b1v = *(const float4*)(xB + xo + 4);
      bf16x8 ahiA, aloA, ahiB, aloB;
      cvt_hilo(a0, a1v, &ahiA, &aloA);
      cvt_hilo(b0, b1v, &ahiB, &aloB);

      #pragma unroll
      for (int ct = 0; ct < 4; ct++){
        int wcol = ct * 16 + col16;
        const bf16x8 bhi = *(const bf16x8*)(&ldsB[0][wcol * 68 + kt * 16 + kg * 4]);
        const bf16x8 blo = *(const bf16x8*)(&ldsB[1][wcol * 68 + kt * 16 + kg * 4]);
        accA[ct] = __builtin_amdgcn_mfma_f32_16x16x32_bf16(ahiA, bhi, accA[ct], 0, 0, 0);
        accA[ct] = __builtin_amdgcn_mfma_f32_16x16x32_bf16(ahiA, blo, accA[ct], 0, 0, 0);
        accA[ct] = __builtin_amdgcn_mfma_f32_16x16x32_bf16(aloA, bhi, accA[ct], 0, 0, 0);
        accB[ct] = __builtin_amdgcn_mfma_f32_16x16x32_bf16(ahiB, bhi, accB[ct], 0, 0, 0);
        accB[ct] = __builtin_amdgcn_mfma_f32_16x16x32_bf16(ahiB, blo, accB[ct], 0, 0, 0);
        accB[ct] = __builtin_amdgcn_mfma_f32_16x16x32_bf16(aloB, bhi, accB[ct], 0, 0, 0);
      }
    }
    if (half == 0) __syncthreads();          // all waves done reading before restage
  }

  if (rA < N) epi1(accA, rA, col16, kg, a1s, a1d, h1b, as_, ad_, N);
  if (rB < N) epi1(accB, rB, col16, kg, a1s, a1d, h1b, as_, ad_, N);
}

// ============ layer-1 per-dst gather: staged srcids, MLP-4 channel phase ============
__global__ __launch_bounds__(256) void k_gat1(const unsigned* __restrict__ off_, const unsigned* __restrict__ cur,
    const int* __restrict__ srcids, const float* __restrict__ as_, const float* __restrict__ ad_,
    const unsigned short* __restrict__ h1b, const float* __restrict__ b1,
    unsigned short* __restrict__ out1b, int N){
  int lane = threadIdx.x & 63;
  int wv   = threadIdx.x >> 6;
  int d    = blockIdx.x * 4 + wv;
  if (d >= N) return;
  __shared__ float lds_p[4][64 * 8];
  __shared__ int   lds_s[4][64];
  float* lp = lds_p[wv];
  int*   ls = lds_s[wv];
  unsigned beg = off_[d], fin = cur[d];

  int e8 = lane >> 3, h = lane & 7;                  // exp-phase layout
  int c0 = lane & 31, pe = lane >> 5, hh = c0 >> 2;  // channel-phase layout
  float adh = ad_[(size_t)d * 8 + h];
  float psacc = 0.f, accx = 0.f, accy = 0.f;

  for (unsigned base = beg; base < fin; base += 64){
    int nthis = (int)min(64u, fin - base);
    unsigned i = base + lane;
    ls[lane] = (i < fin) ? srcids[i] : 0;            // one coalesced stage
    asm volatile("s_waitcnt lgkmcnt(0)" ::: "memory");
    __builtin_amdgcn_sched_barrier(0);
    for (int j = 0; j < nthis; j += 8){
      int eloc = j + e8;
      int s = ls[eloc];
      float p = 0.f;
      if (eloc < nthis) p = __expf(lrelu(as_[(size_t)s * 8 + h] + adh));
      lp[eloc * 8 + h] = p;
      psacc += p;
    }
    asm volatile("s_waitcnt lgkmcnt(0)" ::: "memory");
    __builtin_amdgcn_sched_barrier(0);
    for (int e = 0; e < nthis; e += 8){
      int e0 = e + pe, e1 = e + 2 + pe, e2 = e + 4 + pe, e3 = e + 6 + pe;
      float p0 = lp[e0 * 8 + hh], p1 = lp[e1 * 8 + hh];
      float p2 = lp[e2 * 8 + hh], p3 = lp[e3 * 8 + hh];
      int s0 = ls[e0], s1 = ls[e1], s2 = ls[e2], s3 = ls[e3];
      unsigned u0 = *(const unsigned*)(h1b + (size_t)s0 * 64 + c0 * 2);
      unsigned u1 = *(const unsigned*)(h1b + (size_t)s1 * 64 + c0 * 2);
      unsigned u2 = *(const unsigned*)(h1b + (size_t)s2 * 64 + c0 * 2);
      unsigned u3 = *(const unsigned*)(h1b + (size_t)s3 * 64 + c0 * 2);
      accx = fmaf(p0, __uint_as_float(u0 << 16), accx);
      accy = fmaf(p0, __uint_as_float(u0 & 0xFFFF0000u), accy);
      accx = fmaf(p1, __uint_as_float(u1 << 16), accx);
      accy = fmaf(p1, __uint_as_float(u1 & 0xFFFF0000u), accy);
      accx = fmaf(p2, __uint_as_float(u2 << 16), accx);
      accy = fmaf(p2, __uint_as_float(u2 & 0xFFFF0000u), accy);
      accx = fmaf(p3, __uint_as_float(u3 << 16), accx);
      accy = fmaf(p3, __uint_as_float(u3 & 0xFFFF0000u), accy);
    }
    asm volatile("" ::: "memory");
  }
  float den = psacc;
  den += __shfl_xor(den, 8, 64);
  den += __shfl_xor(den, 16, 64);
  den += __shfl_xor(den, 32, 64);
  float mydenv = __shfl(den, hh, 64);
  accx += __shfl_xor(accx, 32, 64);
  accy += __shfl_xor(accy, 32, 64);
  if (lane < 32){
    int ch = lane * 2;
    float v0 = accx / mydenv + b1[ch];
    float v1 = accy / mydenv + b1[ch + 1];
    ushort2 o;
    o.x = f2bf(v0 > 0.f ? v0 : 0.f);
    o.y = f2bf(v1 > 0.f ? v1 : 0.f);
    *(ushort2*)(out1b + (size_t)d * 64 + ch) = o;
  }
}

// ============ GEMM2 via MFMA (bf16 A, hi/lo B) + fused alpha2 ============
__global__ __launch_bounds__(256) void k_gemm2m(const unsigned short* __restrict__ out1b,
    const short* __restrict__ wt2_hi, const short* __restrict__ wt2_lo,
    const float* __restrict__ a2s, const float* __restrict__ a2d,
    unsigned short* __restrict__ h2b, float* __restrict__ as_, float* __restrict__ ad_, int N){
  int lane = threadIdx.x & 63;
  int wv   = threadIdx.x >> 6;
  int r0   = blockIdx.x * 64 + wv * 16;
  if (r0 >= N) return;
  int col16 = lane & 15;
  int kg    = lane >> 4;
  const unsigned short* ar = out1b + (size_t)min(r0 + col16, N - 1) * 64 + kg * 8;

  f32x4 acc[3];
  #pragma unroll
  for (int ct = 0; ct < 3; ct++) acc[ct] = (f32x4){0.f, 0.f, 0.f, 0.f};

  #pragma unroll
  for (int kt = 0; kt < 2; kt++){
    const bf16x8 a = *(const bf16x8*)(ar + kt * 32);
    #pragma unroll
    for (int ct = 0; ct < 3; ct++){
      int wcol = ct * 16 + col16;
      const bf16x8 bhi = *(const bf16x8*)(wt2_hi + wcol * 64 + kt * 32 + kg * 8);
      const bf16x8 blo = *(const bf16x8*)(wt2_lo + wcol * 64 + kt * 32 + kg * 8);
      acc[ct] = __builtin_amdgcn_mfma_f32_16x16x32_bf16(a, bhi, acc[ct], 0, 0, 0);
      acc[ct] = __builtin_amdgcn_mfma_f32_16x16x32_bf16(a, blo, acc[ct], 0, 0, 0);
    }
  }

  float cs[3], cd[3];
  #pragma unroll
  for (int ct = 0; ct < 3; ct++){
    int col = ct * 16 + col16;
    bool okc = col < 40;
    cs[ct] = okc ? a2s[col] : 0.f;
    cd[ct] = okc ? a2d[col] : 0.f;
  }
  #pragma unroll
  for (int r = 0; r < 4; r++){
    int rr = r0 + kg * 4 + r;
    bool ok = rr < N;
    float s = 0.f, t = 0.f;
    #pragma unroll
    for (int ct = 0; ct < 3; ct++){
      s = fmaf(acc[ct][r], cs[ct], s);
      t = fmaf(acc[ct][r], cd[ct], t);
      int col = ct * 16 + col16;
      if (ok && col < 40) h2b[(size_t)rr * 40 + col] = f2bf(acc[ct][r]);
    }
    s += __shfl_xor(s, 1, 64); s += __shfl_xor(s, 2, 64);
    s += __shfl_xor(s, 4, 64); s += __shfl_xor(s, 8, 64);
    t += __shfl_xor(t, 1, 64); t += __shfl_xor(t, 2, 64);
    t += __shfl_xor(t, 4, 64); t += __shfl_xor(t, 8, 64);
    if (ok && col16 == 0){ as_[rr] = s; ad_[rr] = t; }
  }
}

// ============ layer-2 per-dst gather (H=1, C=40), MLP-4 + fused bias+log_softmax ============
__global__ __launch_bounds__(256) void k_gat2(const unsigned* __restrict__ off_, const unsigned* __restrict__ cur,
    const int* __restrict__ srcids, const float* __restrict__ as_, const float* __restrict__ ad_,
    const unsigned short* __restrict__ h2b, const float* __restrict__ b2, float* __restrict__ out, int N){
  int lane = threadIdx.x & 63;
  int wv   = threadIdx.x >> 6;
  int d    = blockIdx.x * 4 + wv;
  if (d >= N) return;
  __shared__ float lds_p[4][64];
  __shared__ int   lds_s[4][64];
  float* lp = lds_p[wv];
  int*   ls = lds_s[wv];
  unsigned beg = off_[d], fin = cur[d];
  float add = ad_[d];

  int c0 = lane & 31;
  int pe = lane >> 5;
  int idx = c0 < 20 ? c0 : 19;
  float ps = 0.f, accx = 0.f, accy = 0.f;

  for (unsigned base = beg; base < fin; base += 64){
    unsigned i = base + lane;
    int nthis = (int)min(64u, fin - base);
    if (i < fin){
      int s = srcids[i];
      float p = __expf(lrelu(as_[s] + add));
      ps += p; ls[lane] = s; lp[lane] = p;
    } else { ls[lane] = 0; lp[lane] = 0.f; }
    asm volatile("s_waitcnt lgkmcnt(0)" ::: "memory");
    __builtin_amdgcn_sched_barrier(0);
    for (int e = 0; e < nthis; e += 8){
      int e0 = e + pe, e1 = e + 2 + pe, e2 = e + 4 + pe, e3 = e + 6 + pe;
      float p0 = lp[e0], p1 = lp[e1], p2 = lp[e2], p3 = lp[e3];
      int s0 = ls[e0], s1 = ls[e1], s2 = ls[e2], s3 = ls[e3];
      unsigned u0 = *(const unsigned*)(h2b + (size_t)s0 * 40 + idx * 2);
      unsigned u1 = *(const unsigned*)(h2b + (size_t)s1 * 40 + idx * 2);
      unsigned u2 = *(const unsigned*)(h2b + (size_t)s2 * 40 + idx * 2);
      unsigned u3 = *(const unsigned*)(h2b + (size_t)s3 * 40 + idx * 2);
      accx = fmaf(p0, __uint_as_float(u0 << 16), accx);
      accy = fmaf(p0, __uint_as_float(u0 & 0xFFFF0000u), accy);
      accx = fmaf(p1, __uint_as_float(u1 << 16), accx);
      accy = fmaf(p1, __uint_as_float(u1 & 0xFFFF0000u), accy);
      accx = fmaf(p2, __uint_as_float(u2 << 16), accx);
      accy = fmaf(p2, __uint_as_float(u2 & 0xFFFF0000u), accy);
      accx = fmaf(p3, __uint_as_float(u3 << 16), accx);
      accy = fmaf(p3, __uint_as_float(u3 & 0xFFFF0000u), accy);
    }
    asm volatile("" ::: "memory");
  }
  ps = wred_sum(ps);
  accx += __shfl_xor(accx, 32, 64);
  accy += __shfl_xor(accy, 32, 64);

  float v0 = accx / ps + b2[idx * 2];
  float v1 = accy / ps + b2[idx * 2 + 1];
  bool act = (c0 < 20);
  float mx = act ? fmaxf(v0, v1) : -INFINITY;
  #pragma unroll
  for (int o = 16; o; o >>= 1) mx = fmaxf(mx, __shfl_xor(mx, o, 64));
  float exs = act ? (__expf(v0 - mx) + __expf(v1 - mx)) : 0.f;
  #pragma unroll
  for (int o = 16; o; o >>= 1) exs += __shfl_xor(exs, o, 64);
  float lse = mx + logf(exs);
  if (lane < 20){
    float2 o2; o2.x = v0 - lse; o2.y = v1 - lse;
    *(float2*)(out + (size_t)d * 40 + lane * 2) = o2;
  }
}

extern "C" void kernel_launch(void* const* d_in, const int* in_sizes, int n_in,
                              void* d_out, int out_size, void* d_ws, size_t ws_size,
                              hipStream_t stream){
  const float* x   = (const float*)d_in[0];
  const int*   ei  = (const int*)d_in[1];
  const float* W1  = (const float*)d_in[2];
  const float* a1s = (const float*)d_in[3];
  const float* a1d = (const float*)d_in[4];
  const float* b1  = (const float*)d_in[5];
  const float* W2  = (const float*)d_in[6];
  const float* a2s = (const float*)d_in[7];
  const float* a2d = (const float*)d_in[8];
  const float* b2  = (const float*)d_in[9];
  float* out = (float*)d_out;

  const int N = in_sizes[0] / 256;
  const int E = in_sizes[1] / 2;
  const int tot = E + N;
  const int nb  = (N + 255) >> 8;

  float* ws = (float*)d_ws;
  size_t o = 0;
  float* as1  = ws + o; o += (size_t)N * 8;
  float* ad1  = ws + o; o += (size_t)N * 8;
  unsigned short* out1b = (unsigned short*)(ws + o); o += (size_t)N * 32;  // aliases `staged`
  unsigned short* h1b   = (unsigned short*)(ws + o); o += (size_t)N * 32;
  unsigned short* h2b   = (unsigned short*)(ws + o); o += (size_t)N * 20;
  unsigned* off_ = (unsigned*)(ws + o); o += (size_t)N;
  unsigned* cur  = (unsigned*)(ws + o); o += (size_t)N;
  int* srcids    = (int*)(ws + o);      o += (size_t)tot;
  short* wt_hi   = (short*)(ws + o);    o += 8192;   // 16384 bf16
  short* wt_lo   = (short*)(ws + o);    o += 8192;
  short* wt2_hi  = (short*)(ws + o);    o += 1536;   // 3072 bf16 (48x64)
  short* wt2_lo  = (short*)(ws + o);    o += 1536;
  unsigned* bcnt  = (unsigned*)(ws + o); o += nb;
  unsigned* bbase = (unsigned*)(ws + o); o += nb + 1;
  unsigned* bcur  = (unsigned*)(ws + o); o += nb;
  unsigned* staged = (unsigned*)out1b;
  float* as2 = as1;
  float* ad2 = ad1;

  const int cb = (tot + 8191) / 8192;

  hipMemsetAsync(bcnt, 0, sizeof(unsigned) * (size_t)nb, stream);

  // bucketed CSR build
  k_bincnt <<<cb, 256, 0, stream>>>(ei, E, N, nb, bcnt);
  k_bscan  <<<1, 512, 0, stream>>>(bcnt, bbase, bcur, nb, tot);
  k_binscat<<<cb, 256, 0, stream>>>(ei, E, N, nb, bcur, staged);
  k_csr    <<<nb, 256, 0, stream>>>(bbase, staged, N, off_, cur, srcids);

  // weight prep
  k_wprep <<<64, 256, 0, stream>>>(W1, wt_hi, wt_lo);
  k_w2prep<<<12, 256, 0, stream>>>(W2, wt2_hi, wt2_lo);

  // layer 1
  k_gemm1_mfma<<<(N + 127) / 128, 256, 0, stream>>>(x, (const unsigned*)wt_hi, (const unsigned*)wt_lo,
                                                    a1s, a1d, h1b, as1, ad1, N);
  k_gat1 <<<(N + 3) / 4, 256, 0, stream>>>(off_, cur, srcids, as1, ad1, h1b, b1, out1b, N);

  // layer 2
  k_gemm2m<<<(N + 63) / 64, 256, 0, stream>>>(out1b, wt2_hi, wt2_lo, a2s, a2d, h2b, as2, ad2, N);
  k_gat2  <<<(N + 3) / 4, 256, 0, stream>>>(off_, cur, srcids, as2, ad2, h2b, b2, out, N);
}

// Round 17
// 224.685 us; speedup vs baseline: 1.1748x; 1.0421x over previous
//
#include <hip/hip_runtime.h>
#include <math.h>

#define NEG_SLOPE 0.2f
__device__ __forceinline__ float lrelu(float x){ return x >= 0.f ? x : NEG_SLOPE * x; }

typedef __attribute__((ext_vector_type(8))) short bf16x8;
typedef __attribute__((ext_vector_type(4))) float f32x4;

__device__ __forceinline__ float wred_sum(float v){
  #pragma unroll
  for (int o = 32; o; o >>= 1) v += __shfl_xor(v, o, 64);
  return v;
}

__device__ __forceinline__ float bfhi_f(float f){
  return __uint_as_float(__float_as_uint(f) & 0xFFFF0000u);
}
// fp32 -> bf16 RTNE
__device__ __forceinline__ unsigned short f2bf(float f){
  unsigned u = __float_as_uint(f);
  unsigned r = u + 0x7FFFu + ((u >> 16) & 1u);
  return (unsigned short)(r >> 16);
}

// ================= fused prep: bincnt || wprep || w2prep =================
__global__ __launch_bounds__(256) void k_prep(const int* __restrict__ ei, int E, int N, int nb, int cb,
    unsigned* __restrict__ bcnt,
    const float* __restrict__ W1, short* __restrict__ wt_hi, short* __restrict__ wt_lo,
    const float* __restrict__ W2, short* __restrict__ wt2_hi, short* __restrict__ wt2_lo){
  __shared__ unsigned h[512];
  int bid = blockIdx.x;
  if (bid < cb){
    // ---- bincnt role ----
    const int tot = E + N;
    for (int i = threadIdx.x; i < nb; i += 256) h[i] = 0;
    __syncthreads();
    int base = bid * 8192;
    #pragma unroll 4
    for (int j = 0; j < 32; j++){
      int e = base + threadIdx.x + j * 256;
      if (e < tot){
        unsigned d = (e < E) ? (unsigned)ei[E + e] : (unsigned)(e - E);
        atomicAdd(&h[d >> 8], 1u);
      }
    }
    __syncthreads();
    for (int i = threadIdx.x; i < nb; i += 256)
      if (h[i]) atomicAdd(&bcnt[i], h[i]);
  } else if (bid < cb + 64){
    // ---- wprep role: Wt_hi/Wt_lo[64][256] bf16 ----
    int i = (bid - cb) * 256 + threadIdx.x;    // 16384
    int k = i >> 6, c = i & 63;
    float v = W1[i];
    unsigned u = __float_as_uint(v);
    wt_hi[c * 256 + k] = (short)(u >> 16);
    float lo = v - bfhi_f(v);
    wt_lo[c * 256 + k] = (short)(__float_as_uint(lo) >> 16);
  } else {
    // ---- w2prep role: [48][64] bf16 hi/lo (cols 40-47 zero) ----
    int i = (bid - cb - 64) * 256 + threadIdx.x;  // 3072
    if (i < 48 * 64){
      int c = i >> 6, k = i & 63;
      float v = (c < 40) ? W2[k * 40 + c] : 0.f;
      unsigned u = __float_as_uint(v);
      wt2_hi[c * 64 + k] = (short)(u >> 16);
      float l = v - bfhi_f(v);
      wt2_lo[c * 64 + k] = (short)(__float_as_uint(l) >> 16);
    }
  }
}

__global__ void k_bscan(const unsigned* __restrict__ bcnt, unsigned* __restrict__ bbase,
                        unsigned* __restrict__ bcur, int nb, int tot){
  __shared__ unsigned s[512];
  int t = threadIdx.x;
  unsigned v = (t < nb) ? bcnt[t] : 0u;
  s[t] = v; __syncthreads();
  for (int off = 1; off < 512; off <<= 1){
    unsigned x = (t >= off) ? s[t - off] : 0u; __syncthreads();
    s[t] += x; __syncthreads();
  }
  if (t < nb){ unsigned b = s[t] - v; bbase[t] = b; bcur[t] = b; }
  if (t == 0) bbase[nb] = (unsigned)tot;
}

__global__ __launch_bounds__(256) void k_binscat(const int* __restrict__ ei, int E, int N, int nb,
    unsigned* __restrict__ bcur, unsigned* __restrict__ staged){
  __shared__ unsigned sd[8192];
  __shared__ unsigned hist[512];
  __shared__ unsigned runb[512];
  const int tot = E + N;
  for (int i = threadIdx.x; i < nb; i += 256) hist[i] = 0;
  __syncthreads();
  int base = blockIdx.x * 8192;
  #pragma unroll 4
  for (int j = 0; j < 32; j++){
    int idx = threadIdx.x + j * 256;
    int e = base + idx;
    unsigned d = 0xFFFFFFFFu;
    if (e < tot) d = (e < E) ? (unsigned)ei[E + e] : (unsigned)(e - E);
    sd[idx] = d;
    if (d != 0xFFFFFFFFu) atomicAdd(&hist[d >> 8], 1u);
  }
  __syncthreads();
  for (int i = threadIdx.x; i < nb; i += 256){
    unsigned c = hist[i];
    runb[i] = c ? atomicAdd(&bcur[i], c) : 0u;
    hist[i] = 0;
  }
  __syncthreads();
  #pragma unroll 4
  for (int j = 0; j < 32; j++){
    int idx = threadIdx.x + j * 256;
    unsigned d = sd[idx];
    if (d == 0xFFFFFFFFu) continue;
    int e = base + idx;
    unsigned s = (e < E) ? (unsigned)ei[e] : d;
    unsigned b = d >> 8;
    unsigned pos = runb[b] + atomicAdd(&hist[b], 1u);
    staged[pos] = s | ((d & 255u) << 20);
  }
}

// ============ fused: csr (blocks < nb) || gemm1-R15 (blocks >= nb) ============
// csr consumes binscat output; gemm1 consumes k_prep's weight tables; the only
// consumer of BOTH (gat1) launches after this kernel. csr's ~15us hides under
// gemm1's ~73us. LDS is the union (gemm1's 67.6KB B-table stage — the R15 lever
// that broke the TA address-rate wall by removing 64 B-load instrs per wave).
__global__ __launch_bounds__(256) void k_csrgemm1(
    const unsigned* __restrict__ bbase, const unsigned* __restrict__ staged, int nb,
    unsigned* __restrict__ off_, unsigned* __restrict__ cur, int* __restrict__ srcids,
    const float* __restrict__ x,
    const unsigned* __restrict__ wtu_hi, const unsigned* __restrict__ wtu_lo,
    const float* __restrict__ a1s, const float* __restrict__ a1d,
    unsigned short* __restrict__ h1b, float* __restrict__ as_, float* __restrict__ ad_, int N){
  __shared__ union {
    struct { unsigned cnt[256], scn[256], cnt2[256]; } c;
    unsigned B[2][64 * 132];                 // [hi|lo][64 rows x (128 data + 4 pad) u32]
  } sm;

  if (blockIdx.x < nb){
    // ---- csr role ----
    int b = blockIdx.x, t = threadIdx.x;
    unsigned beg = bbase[b], end = bbase[b + 1];
    sm.c.cnt[t] = 0; sm.c.cnt2[t] = 0;
    __syncthreads();
    for (unsigned i = beg + t; i < end; i += 256)
      atomicAdd(&sm.c.cnt[staged[i] >> 20], 1u);
    __syncthreads();
    unsigned v = sm.c.cnt[t];
    sm.c.scn[t] = v; __syncthreads();
    for (int off = 1; off < 256; off <<= 1){
      unsigned xval = (t >= off) ? sm.c.scn[t - off] : 0u; __syncthreads();
      sm.c.scn[t] += xval; __syncthreads();
    }
    unsigned ex = sm.c.scn[t] - v;
    int d = b * 256 + t;
    if (d < N){ off_[d] = beg + ex; cur[d] = beg + ex + v; }
    sm.c.cnt[t] = ex;
    __syncthreads();
    for (unsigned i = beg + t; i < end; i += 256){
      unsigned u = staged[i];
      unsigned dl = u >> 20;
      unsigned pos = beg + sm.c.cnt[dl] + atomicAdd(&sm.c.cnt2[dl], 1u);
      srcids[pos] = (int)(u & 0xFFFFFu);
    }
    return;
  }

  // ---- gemm1 role (R15 body: full-K B-stage in LDS) ----
  int bid  = blockIdx.x - nb;
  int lane = threadIdx.x & 63;
  int wv   = threadIdx.x >> 6;
  int r0   = bid * 64 + wv * 16;
  int col16 = lane & 15;
  int kg    = lane >> 4;

  #pragma unroll
  for (int j = 0; j < 32; j++){
    int g = threadIdx.x + j * 256;
    int row = g >> 7, col = g & 127;
    sm.B[0][row * 132 + col] = wtu_hi[g];
    sm.B[1][row * 132 + col] = wtu_lo[g];
  }
  __syncthreads();
  if (r0 >= N) return;

  const float* xr = x + (size_t)min(r0 + col16, N - 1) * 256 + kg * 8;

  f32x4 acc[4];
  #pragma unroll
  for (int ct = 0; ct < 4; ct++) acc[ct] = (f32x4){0.f, 0.f, 0.f, 0.f};

  #pragma unroll 2
  for (int kt = 0; kt < 8; kt++){
    float4 v0 = *(const float4*)(xr + kt * 32);
    float4 v1 = *(const float4*)(xr + kt * 32 + 4);
    unsigned u[8] = {__float_as_uint(v0.x), __float_as_uint(v0.y), __float_as_uint(v0.z), __float_as_uint(v0.w),
                     __float_as_uint(v1.x), __float_as_uint(v1.y), __float_as_uint(v1.z), __float_as_uint(v1.w)};
    union { bf16x8 v; unsigned u[4]; } ahi, alo;
    #pragma unroll
    for (int j = 0; j < 4; j++)
      ahi.u[j] = __builtin_amdgcn_perm(u[2*j+1], u[2*j], 0x07060302);
    float lo[8];
    lo[0] = v0.x - bfhi_f(v0.x); lo[1] = v0.y - bfhi_f(v0.y);
    lo[2] = v0.z - bfhi_f(v0.z); lo[3] = v0.w - bfhi_f(v0.w);
    lo[4] = v1.x - bfhi_f(v1.x); lo[5] = v1.y - bfhi_f(v1.y);
    lo[6] = v1.z - bfhi_f(v1.z); lo[7] = v1.w - bfhi_f(v1.w);
    #pragma unroll
    for (int j = 0; j < 4; j++)
      alo.u[j] = __builtin_amdgcn_perm(__float_as_uint(lo[2*j+1]), __float_as_uint(lo[2*j]), 0x07060302);

    #pragma unroll
    for (int ct = 0; ct < 4; ct++){
      int wcol = ct * 16 + col16;
      const bf16x8 bhi = *(const bf16x8*)(&sm.B[0][wcol * 132 + kt * 16 + kg * 4]);
      const bf16x8 blo = *(const bf16x8*)(&sm.B[1][wcol * 132 + kt * 16 + kg * 4]);
      acc[ct] = __builtin_amdgcn_mfma_f32_16x16x32_bf16(ahi.v, bhi, acc[ct], 0, 0, 0);
      acc[ct] = __builtin_amdgcn_mfma_f32_16x16x32_bf16(ahi.v, blo, acc[ct], 0, 0, 0);
      acc[ct] = __builtin_amdgcn_mfma_f32_16x16x32_bf16(alo.v, bhi, acc[ct], 0, 0, 0);
    }
  }

  float cs[4], cd[4];
  #pragma unroll
  for (int ct = 0; ct < 4; ct++){ cs[ct] = a1s[ct * 16 + col16]; cd[ct] = a1d[ct * 16 + col16]; }
  #pragma unroll
  for (int r = 0; r < 4; r++){
    int rr = r0 + kg * 4 + r;
    bool ok = rr < N;
    #pragma unroll
    for (int ct = 0; ct < 4; ct++){
      float v = acc[ct][r];
      if (ok) h1b[(size_t)rr * 64 + ct * 16 + col16] = f2bf(v);
      float s = v * cs[ct];
      float t = v * cd[ct];
      s += __shfl_xor(s, 1, 64); s += __shfl_xor(s, 2, 64); s += __shfl_xor(s, 4, 64);
      t += __shfl_xor(t, 1, 64); t += __shfl_xor(t, 2, 64); t += __shfl_xor(t, 4, 64);
      if (ok && (col16 & 7) == 0){
        int head = ct * 2 + (col16 >> 3);
        as_[(size_t)rr * 8 + head] = s;
        ad_[(size_t)rr * 8 + head] = t;
      }
    }
  }
}

// ============ layer-1 per-dst gather: staged srcids, MLP-4 channel phase ============
__global__ __launch_bounds__(256) void k_gat1(const unsigned* __restrict__ off_, const unsigned* __restrict__ cur,
    const int* __restrict__ srcids, const float* __restrict__ as_, const float* __restrict__ ad_,
    const unsigned short* __restrict__ h1b, const float* __restrict__ b1,
    unsigned short* __restrict__ out1b, int N){
  int lane = threadIdx.x & 63;
  int wv   = threadIdx.x >> 6;
  int d    = blockIdx.x * 4 + wv;
  if (d >= N) return;
  __shared__ float lds_p[4][64 * 8];
  __shared__ int   lds_s[4][64];
  float* lp = lds_p[wv];
  int*   ls = lds_s[wv];
  unsigned beg = off_[d], fin = cur[d];

  int e8 = lane >> 3, h = lane & 7;                  // exp-phase layout
  int c0 = lane & 31, pe = lane >> 5, hh = c0 >> 2;  // channel-phase layout
  float adh = ad_[(size_t)d * 8 + h];
  float psacc = 0.f, accx = 0.f, accy = 0.f;

  for (unsigned base = beg; base < fin; base += 64){
    int nthis = (int)min(64u, fin - base);
    unsigned i = base + lane;
    ls[lane] = (i < fin) ? srcids[i] : 0;            // one coalesced stage
    asm volatile("s_waitcnt lgkmcnt(0)" ::: "memory");
    __builtin_amdgcn_sched_barrier(0);
    for (int j = 0; j < nthis; j += 8){
      int eloc = j + e8;
      int s = ls[eloc];
      float p = 0.f;
      if (eloc < nthis) p = __expf(lrelu(as_[(size_t)s * 8 + h] + adh));
      lp[eloc * 8 + h] = p;
      psacc += p;
    }
    asm volatile("s_waitcnt lgkmcnt(0)" ::: "memory");
    __builtin_amdgcn_sched_barrier(0);
    for (int e = 0; e < nthis; e += 8){
      int e0 = e + pe, e1 = e + 2 + pe, e2 = e + 4 + pe, e3 = e + 6 + pe;
      float p0 = lp[e0 * 8 + hh], p1 = lp[e1 * 8 + hh];
      float p2 = lp[e2 * 8 + hh], p3 = lp[e3 * 8 + hh];
      int s0 = ls[e0], s1 = ls[e1], s2 = ls[e2], s3 = ls[e3];
      unsigned u0 = *(const unsigned*)(h1b + (size_t)s0 * 64 + c0 * 2);
      unsigned u1 = *(const unsigned*)(h1b + (size_t)s1 * 64 + c0 * 2);
      unsigned u2 = *(const unsigned*)(h1b + (size_t)s2 * 64 + c0 * 2);
      unsigned u3 = *(const unsigned*)(h1b + (size_t)s3 * 64 + c0 * 2);
      accx = fmaf(p0, __uint_as_float(u0 << 16), accx);
      accy = fmaf(p0, __uint_as_float(u0 & 0xFFFF0000u), accy);
      accx = fmaf(p1, __uint_as_float(u1 << 16), accx);
      accy = fmaf(p1, __uint_as_float(u1 & 0xFFFF0000u), accy);
      accx = fmaf(p2, __uint_as_float(u2 << 16), accx);
      accy = fmaf(p2, __uint_as_float(u2 & 0xFFFF0000u), accy);
      accx = fmaf(p3, __uint_as_float(u3 << 16), accx);
      accy = fmaf(p3, __uint_as_float(u3 & 0xFFFF0000u), accy);
    }
    asm volatile("" ::: "memory");
  }
  float den = psacc;
  den += __shfl_xor(den, 8, 64);
  den += __shfl_xor(den, 16, 64);
  den += __shfl_xor(den, 32, 64);
  float mydenv = __shfl(den, hh, 64);
  accx += __shfl_xor(accx, 32, 64);
  accy += __shfl_xor(accy, 32, 64);
  if (lane < 32){
    int ch = lane * 2;
    float v0 = accx / mydenv + b1[ch];
    float v1 = accy / mydenv + b1[ch + 1];
    ushort2 o;
    o.x = f2bf(v0 > 0.f ? v0 : 0.f);
    o.y = f2bf(v1 > 0.f ? v1 : 0.f);
    *(ushort2*)(out1b + (size_t)d * 64 + ch) = o;
  }
}

// ============ GEMM2 via MFMA (bf16 A, hi/lo B) + fused alpha2 ============
__global__ __launch_bounds__(256) void k_gemm2m(const unsigned short* __restrict__ out1b,
    const short* __restrict__ wt2_hi, const short* __restrict__ wt2_lo,
    const float* __restrict__ a2s, const float* __restrict__ a2d,
    unsigned short* __restrict__ h2b, float* __restrict__ as_, float* __restrict__ ad_, int N){
  int lane = threadIdx.x & 63;
  int wv   = threadIdx.x >> 6;
  int r0   = blockIdx.x * 64 + wv * 16;
  if (r0 >= N) return;
  int col16 = lane & 15;
  int kg    = lane >> 4;
  const unsigned short* ar = out1b + (size_t)min(r0 + col16, N - 1) * 64 + kg * 8;

  f32x4 acc[3];
  #pragma unroll
  for (int ct = 0; ct < 3; ct++) acc[ct] = (f32x4){0.f, 0.f, 0.f, 0.f};

  #pragma unroll
  for (int kt = 0; kt < 2; kt++){
    const bf16x8 a = *(const bf16x8*)(ar + kt * 32);
    #pragma unroll
    for (int ct = 0; ct < 3; ct++){
      int wcol = ct * 16 + col16;
      const bf16x8 bhi = *(const bf16x8*)(wt2_hi + wcol * 64 + kt * 32 + kg * 8);
      const bf16x8 blo = *(const bf16x8*)(wt2_lo + wcol * 64 + kt * 32 + kg * 8);
      acc[ct] = __builtin_amdgcn_mfma_f32_16x16x32_bf16(a, bhi, acc[ct], 0, 0, 0);
      acc[ct] = __builtin_amdgcn_mfma_f32_16x16x32_bf16(a, blo, acc[ct], 0, 0, 0);
    }
  }

  float cs[3], cd[3];
  #pragma unroll
  for (int ct = 0; ct < 3; ct++){
    int col = ct * 16 + col16;
    bool okc = col < 40;
    cs[ct] = okc ? a2s[col] : 0.f;
    cd[ct] = okc ? a2d[col] : 0.f;
  }
  #pragma unroll
  for (int r = 0; r < 4; r++){
    int rr = r0 + kg * 4 + r;
    bool ok = rr < N;
    float s = 0.f, t = 0.f;
    #pragma unroll
    for (int ct = 0; ct < 3; ct++){
      s = fmaf(acc[ct][r], cs[ct], s);
      t = fmaf(acc[ct][r], cd[ct], t);
      int col = ct * 16 + col16;
      if (ok && col < 40) h2b[(size_t)rr * 40 + col] = f2bf(acc[ct][r]);
    }
    s += __shfl_xor(s, 1, 64); s += __shfl_xor(s, 2, 64);
    s += __shfl_xor(s, 4, 64); s += __shfl_xor(s, 8, 64);
    t += __shfl_xor(t, 1, 64); t += __shfl_xor(t, 2, 64);
    t += __shfl_xor(t, 4, 64); t += __shfl_xor(t, 8, 64);
    if (ok && col16 == 0){ as_[rr] = s; ad_[rr] = t; }
  }
}

// ============ layer-2 per-dst gather (H=1, C=40), MLP-4 + fused bias+log_softmax ============
__global__ __launch_bounds__(256) void k_gat2(const unsigned* __restrict__ off_, const unsigned* __restrict__ cur,
    const int* __restrict__ srcids, const float* __restrict__ as_, const float* __restrict__ ad_,
    const unsigned short* __restrict__ h2b, const float* __restrict__ b2, float* __restrict__ out, int N){
  int lane = threadIdx.x & 63;
  int wv   = threadIdx.x >> 6;
  int d    = blockIdx.x * 4 + wv;
  if (d >= N) return;
  __shared__ float lds_p[4][64];
  __shared__ int   lds_s[4][64];
  float* lp = lds_p[wv];
  int*   ls = lds_s[wv];
  unsigned beg = off_[d], fin = cur[d];
  float add = ad_[d];

  int c0 = lane & 31;
  int pe = lane >> 5;
  int idx = c0 < 20 ? c0 : 19;
  float ps = 0.f, accx = 0.f, accy = 0.f;

  for (unsigned base = beg; base < fin; base += 64){
    unsigned i = base + lane;
    int nthis = (int)min(64u, fin - base);
    if (i < fin){
      int s = srcids[i];
      float p = __expf(lrelu(as_[s] + add));
      ps += p; ls[lane] = s; lp[lane] = p;
    } else { ls[lane] = 0; lp[lane] = 0.f; }
    asm volatile("s_waitcnt lgkmcnt(0)" ::: "memory");
    __builtin_amdgcn_sched_barrier(0);
    for (int e = 0; e < nthis; e += 8){
      int e0 = e + pe, e1 = e + 2 + pe, e2 = e + 4 + pe, e3 = e + 6 + pe;
      float p0 = lp[e0], p1 = lp[e1], p2 = lp[e2], p3 = lp[e3];
      int s0 = ls[e0], s1 = ls[e1], s2 = ls[e2], s3 = ls[e3];
      unsigned u0 = *(const unsigned*)(h2b + (size_t)s0 * 40 + idx * 2);
      unsigned u1 = *(const unsigned*)(h2b + (size_t)s1 * 40 + idx * 2);
      unsigned u2 = *(const unsigned*)(h2b + (size_t)s2 * 40 + idx * 2);
      unsigned u3 = *(const unsigned*)(h2b + (size_t)s3 * 40 + idx * 2);
      accx = fmaf(p0, __uint_as_float(u0 << 16), accx);
      accy = fmaf(p0, __uint_as_float(u0 & 0xFFFF0000u), accy);
      accx = fmaf(p1, __uint_as_float(u1 << 16), accx);
      accy = fmaf(p1, __uint_as_float(u1 & 0xFFFF0000u), accy);
      accx = fmaf(p2, __uint_as_float(u2 << 16), accx);
      accy = fmaf(p2, __uint_as_float(u2 & 0xFFFF0000u), accy);
      accx = fmaf(p3, __uint_as_float(u3 << 16), accx);
      accy = fmaf(p3, __uint_as_float(u3 & 0xFFFF0000u), accy);
    }
    asm volatile("" ::: "memory");
  }
  ps = wred_sum(ps);
  accx += __shfl_xor(accx, 32, 64);
  accy += __shfl_xor(accy, 32, 64);

  float v0 = accx / ps + b2[idx * 2];
  float v1 = accy / ps + b2[idx * 2 + 1];
  bool act = (c0 < 20);
  float mx = act ? fmaxf(v0, v1) : -INFINITY;
  #pragma unroll
  for (int o = 16; o; o >>= 1) mx = fmaxf(mx, __shfl_xor(mx, o, 64));
  float exs = act ? (__expf(v0 - mx) + __expf(v1 - mx)) : 0.f;
  #pragma unroll
  for (int o = 16; o; o >>= 1) exs += __shfl_xor(exs, o, 64);
  float lse = mx + logf(exs);
  if (lane < 20){
    float2 o2; o2.x = v0 - lse; o2.y = v1 - lse;
    *(float2*)(out + (size_t)d * 40 + lane * 2) = o2;
  }
}

extern "C" void kernel_launch(void* const* d_in, const int* in_sizes, int n_in,
                              void* d_out, int out_size, void* d_ws, size_t ws_size,
                              hipStream_t stream){
  const float* x   = (const float*)d_in[0];
  const int*   ei  = (const int*)d_in[1];
  const float* W1  = (const float*)d_in[2];
  const float* a1s = (const float*)d_in[3];
  const float* a1d = (const float*)d_in[4];
  const float* b1  = (const float*)d_in[5];
  const float* W2  = (const float*)d_in[6];
  const float* a2s = (const float*)d_in[7];
  const float* a2d = (const float*)d_in[8];
  const float* b2  = (const float*)d_in[9];
  float* out = (float*)d_out;

  const int N = in_sizes[0] / 256;
  const int E = in_sizes[1] / 2;
  const int tot = E + N;
  const int nb  = (N + 255) >> 8;

  float* ws = (float*)d_ws;
  size_t o = 0;
  float* as1  = ws + o; o += (size_t)N * 8;
  float* ad1  = ws + o; o += (size_t)N * 8;
  unsigned short* out1b = (unsigned short*)(ws + o); o += (size_t)N * 32;  // aliases `staged`
  unsigned short* h1b   = (unsigned short*)(ws + o); o += (size_t)N * 32;
  unsigned short* h2b   = (unsigned short*)(ws + o); o += (size_t)N * 20;
  unsigned* off_ = (unsigned*)(ws + o); o += (size_t)N;
  unsigned* cur  = (unsigned*)(ws + o); o += (size_t)N;
  int* srcids    = (int*)(ws + o);      o += (size_t)tot;
  short* wt_hi   = (short*)(ws + o);    o += 8192;   // 16384 bf16
  short* wt_lo   = (short*)(ws + o);    o += 8192;
  short* wt2_hi  = (short*)(ws + o);    o += 1536;   // 3072 bf16 (48x64)
  short* wt2_lo  = (short*)(ws + o);    o += 1536;
  unsigned* bcnt  = (unsigned*)(ws + o); o += nb;
  unsigned* bbase = (unsigned*)(ws + o); o += nb + 1;
  unsigned* bcur  = (unsigned*)(ws + o); o += nb;
  unsigned* staged = (unsigned*)out1b;
  float* as2 = as1;
  float* ad2 = ad1;

  const int cb = (tot + 8191) / 8192;
  const int gb = (N + 63) / 64;

  hipMemsetAsync(bcnt, 0, sizeof(unsigned) * (size_t)nb, stream);

  // fused prep: edge-bucket histogram || W1 split || W2 split
  k_prep   <<<cb + 64 + 12, 256, 0, stream>>>(ei, E, N, nb, cb, bcnt,
                                              W1, wt_hi, wt_lo, W2, wt2_hi, wt2_lo);
  k_bscan  <<<1, 512, 0, stream>>>(bcnt, bbase, bcur, nb, tot);
  k_binscat<<<cb, 256, 0, stream>>>(ei, E, N, nb, bcur, staged);

  // fused: csr finalize || gemm1 (layer-1 projection + alpha1)
  k_csrgemm1<<<nb + gb, 256, 0, stream>>>(bbase, staged, nb, off_, cur, srcids,
                                          x, (const unsigned*)wt_hi, (const unsigned*)wt_lo,
                                          a1s, a1d, h1b, as1, ad1, N);
  k_gat1 <<<(N + 3) / 4, 256, 0, stream>>>(off_, cur, srcids, as1, ad1, h1b, b1, out1b, N);

  // layer 2
  k_gemm2m<<<(N + 63) / 64, 256, 0, stream>>>(out1b, wt2_hi, wt2_lo, a2s, a2d, h2b, as2, ad2, N);
  k_gat2  <<<(N + 3) / 4, 256, 0, stream>>>(off_, cur, srcids, as2, ad2, h2b, b2, out, N);
}